// Round 1
// baseline (4774.704 us; speedup 1.0000x reference)
//
#include <hip/hip_runtime.h>
#include <math.h>

// Problem constants
constexpr int B_  = 96;
constexpr int C_  = 5;
constexpr int H_  = 256;
constexpr int W_  = 256;
constexpr int T_  = 256;
constexpr int V_  = 256;
constexpr int NH_ = 2;
constexpr int DH_ = 156;
constexpr int E_  = NH_ * DH_;   // 312
constexpr int CV_ = C_ * V_;     // 1280

// ---------------------------------------------------------------------------
// 1) Gather: xt[b, t, ch*V + v] = sino[b, ch, r[t,v], c[t,v]]
// ---------------------------------------------------------------------------
__global__ __launch_bounds__(256)
void gather_kernel(const float* __restrict__ sino, const float* __restrict__ idx,
                   float* __restrict__ xt) {
    size_t i = (size_t)blockIdx.x * blockDim.x + threadIdx.x;
    size_t total = (size_t)B_ * T_ * C_ * V_;
    if (i >= total) return;
    int v  = (int)(i % V_);
    size_t j = i / V_;
    int ch = (int)(j % C_);
    j /= C_;
    int t = (int)(j % T_);
    int b = (int)(j / T_);
    int tv = t * V_ + v;
    int r  = (int)idx[(size_t)tv * 3 + 0];
    int cc = (int)idx[(size_t)tv * 3 + 1];
    xt[i] = sino[(((size_t)b * C_ + ch) * H_ + r) * W_ + cc];
}

// ---------------------------------------------------------------------------
// 2) Generic tiled fp32 GEMM: C[M,N] = epi(A[M,K] @ B[K,N] + bias [+ pos])
//    EPI: 0 = bias only (bias may be null), 1 = bias + pos (pos[t, n], t=m%T_),
//         2 = gelu(x + bias)  (exact gelu, erf)
// ---------------------------------------------------------------------------
template <int EPI>
__global__ __launch_bounds__(256)
void gemm_kernel(const float* __restrict__ A, const float* __restrict__ Bm,
                 const float* __restrict__ bias, const float* __restrict__ pos,
                 float* __restrict__ Cout, int M, int N, int K) {
    constexpr int BM = 64, BN = 64, BK = 16;
    __shared__ float As[BK][BM + 1];
    __shared__ float Bs[BK][BN + 1];
    int tid = threadIdx.x;
    int bx = blockIdx.x, by = blockIdx.y;
    int row0 = by * BM, col0 = bx * BN;
    int tx = tid & 15, ty = tid >> 4;
    float acc[4][4] = {};

    for (int k0 = 0; k0 < K; k0 += BK) {
        // Load A tile (BM x BK): idx -> m = idx/16, k = idx%16
        #pragma unroll
        for (int ld = 0; ld < 4; ++ld) {
            int idx2 = tid + ld * 256;
            int m = idx2 >> 4, k = idx2 & 15;
            int gm = row0 + m, gk = k0 + k;
            As[k][m] = (gm < M && gk < K) ? A[(size_t)gm * K + gk] : 0.f;
        }
        // Load B tile (BK x BN): idx -> k = idx/64, n = idx%64
        #pragma unroll
        for (int ld = 0; ld < 4; ++ld) {
            int idx2 = tid + ld * 256;
            int k = idx2 >> 6, n = idx2 & 63;
            int gk = k0 + k, gn = col0 + n;
            Bs[k][n] = (gk < K && gn < N) ? Bm[(size_t)gk * N + gn] : 0.f;
        }
        __syncthreads();
        #pragma unroll
        for (int k = 0; k < BK; ++k) {
            float a[4], bb[4];
            #pragma unroll
            for (int i = 0; i < 4; ++i) a[i] = As[k][ty * 4 + i];
            #pragma unroll
            for (int j = 0; j < 4; ++j) bb[j] = Bs[k][tx * 4 + j];
            #pragma unroll
            for (int i = 0; i < 4; ++i)
                #pragma unroll
                for (int j = 0; j < 4; ++j) acc[i][j] += a[i] * bb[j];
        }
        __syncthreads();
    }

    #pragma unroll
    for (int i = 0; i < 4; ++i) {
        int gm = row0 + ty * 4 + i;
        if (gm >= M) continue;
        #pragma unroll
        for (int j = 0; j < 4; ++j) {
            int gn = col0 + tx * 4 + j;
            if (gn >= N) continue;
            float v = acc[i][j];
            if (bias) v += bias[gn];
            if (EPI == 1) v += pos[(size_t)(gm % T_) * N + gn];
            if (EPI == 2) v = 0.5f * v * (1.f + erff(v * 0.70710678118654752f));
            Cout[(size_t)gm * N + gn] = v;
        }
    }
}

// ---------------------------------------------------------------------------
// 3) Attention: per (b, h, 8-query group). Q/K/V stored as (B*T, E) rows,
//    head h occupies cols [h*DH, (h+1)*DH).
// ---------------------------------------------------------------------------
__global__ __launch_bounds__(256)
void attn_kernel(const float* __restrict__ Q, const float* __restrict__ Km,
                 const float* __restrict__ Vm, float* __restrict__ Am) {
    constexpr int QPB = 8;
    int blk = blockIdx.x;
    int qg = blk & (T_ / QPB - 1);
    int bh = blk >> 5;               // T_/QPB == 32
    int h = bh % NH_;
    int b = bh / NH_;
    int tid = threadIdx.x;

    __shared__ float qv[DH_];
    __shared__ float att[T_];
    __shared__ float red[256];

    const float scale = rsqrtf((float)DH_);
    size_t base = (size_t)b * T_ * E_ + (size_t)h * DH_;

    for (int qq = 0; qq < QPB; ++qq) {
        int t = qg * QPB + qq;
        if (tid < DH_) qv[tid] = Q[base + (size_t)t * E_ + tid];
        __syncthreads();

        // scores: thread tid = key index
        float s = 0.f;
        {
            const float* krow = Km + base + (size_t)tid * E_;
            #pragma unroll 4
            for (int d = 0; d < DH_; ++d) s += qv[d] * krow[d];
            s *= scale;
        }
        red[tid] = s; __syncthreads();
        for (int off = 128; off > 0; off >>= 1) {
            if (tid < off) red[tid] = fmaxf(red[tid], red[tid + off]);
            __syncthreads();
        }
        float mx = red[0]; __syncthreads();
        float e = expf(s - mx);
        red[tid] = e; __syncthreads();
        for (int off = 128; off > 0; off >>= 1) {
            if (tid < off) red[tid] += red[tid + off];
            __syncthreads();
        }
        float denom = red[0];
        att[tid] = e / denom;
        __syncthreads();

        if (tid < DH_) {
            float acc = 0.f;
            const float* vcol = Vm + base + tid;
            #pragma unroll 4
            for (int k = 0; k < T_; ++k) acc += att[k] * vcol[(size_t)k * E_];
            Am[base + (size_t)t * E_ + tid] = acc;
        }
        __syncthreads();
    }
}

// ---------------------------------------------------------------------------
// 4) LayerNorm of (A + Bi): out = (y - mean) * rsqrt(var + eps) * g + beta
// ---------------------------------------------------------------------------
__global__ __launch_bounds__(256)
void ln_kernel(const float* __restrict__ A, const float* __restrict__ Bi,
               const float* __restrict__ g, const float* __restrict__ beta,
               float* __restrict__ Out) {
    int row = blockIdx.x;
    size_t base = (size_t)row * E_;
    int tid = threadIdx.x;
    __shared__ float red[256];
    __shared__ float red2[256];

    float ya = (tid < E_) ? A[base + tid] + Bi[base + tid] : 0.f;
    float yb = (tid + 256 < E_) ? A[base + tid + 256] + Bi[base + tid + 256] : 0.f;
    red[tid]  = ya + yb;
    red2[tid] = ya * ya + yb * yb;
    __syncthreads();
    for (int off = 128; off > 0; off >>= 1) {
        if (tid < off) { red[tid] += red[tid + off]; red2[tid] += red2[tid + off]; }
        __syncthreads();
    }
    float mean = red[0] / E_;
    float var  = red2[0] / E_ - mean * mean;
    float inv  = rsqrtf(var + 1e-5f);
    if (tid < E_)       Out[base + tid]       = (ya - mean) * inv * g[tid] + beta[tid];
    if (tid + 256 < E_) Out[base + tid + 256] = (yb - mean) * inv * g[tid + 256] + beta[tid + 256];
}

// ---------------------------------------------------------------------------
// 5) Scatter + final add: d_out[b, r, c] = sino[b, C-1, r, c] + out[b,t,v]*sc
// ---------------------------------------------------------------------------
__global__ __launch_bounds__(256)
void scatter_kernel(const float* __restrict__ sino, const float* __restrict__ idx,
                    const float* __restrict__ outm, float* __restrict__ dout) {
    size_t i = (size_t)blockIdx.x * blockDim.x + threadIdx.x;
    size_t total = (size_t)B_ * T_ * V_;
    if (i >= total) return;
    int tv = (int)(i % ((size_t)T_ * V_));
    int b  = (int)(i / ((size_t)T_ * V_));
    int r  = (int)idx[(size_t)tv * 3 + 0];
    int cc = (int)idx[(size_t)tv * 3 + 1];
    float sc = idx[(size_t)tv * 3 + 2];
    size_t pos = (size_t)r * W_ + cc;
    dout[(size_t)b * H_ * W_ + pos] =
        sino[((size_t)b * C_ + (C_ - 1)) * (size_t)H_ * W_ + pos] + outm[i] * sc;
}

// ---------------------------------------------------------------------------
extern "C" void kernel_launch(void* const* d_in, const int* in_sizes, int n_in,
                              void* d_out, int out_size, void* d_ws, size_t ws_size,
                              hipStream_t stream) {
    const float* sino     = (const float*)d_in[0];
    const float* idx      = (const float*)d_in[1];
    const float* We       = (const float*)d_in[2];
    const float* be       = (const float*)d_in[3];
    const float* pos      = (const float*)d_in[4];
    const float* Wq       = (const float*)d_in[5];
    const float* Wk       = (const float*)d_in[6];
    const float* Wv       = (const float*)d_in[7];
    const float* W1       = (const float*)d_in[8];
    const float* b1       = (const float*)d_in[9];
    const float* W2       = (const float*)d_in[10];
    const float* b2       = (const float*)d_in[11];
    const float* W3       = (const float*)d_in[12];
    const float* b3       = (const float*)d_in[13];
    const float* g_att    = (const float*)d_in[14];
    const float* beta_att = (const float*)d_in[15];
    const float* g_mlp    = (const float*)d_in[16];
    const float* beta_mlp = (const float*)d_in[17];
    const float* Wu       = (const float*)d_in[18];
    const float* bu       = (const float*)d_in[19];
    float* out = (float*)d_out;
    float* ws  = (float*)d_ws;

    const size_t XT_SZ = (size_t)B_ * T_ * CV_;   // 31,457,280
    const size_t TE    = (size_t)B_ * T_ * E_;    //  7,667,712

    float* xt = ws;
    float* Zb = ws + XT_SZ;
    float* Qb = Zb + TE;
    float* Kb = Qb + TE;
    float* Vb = Kb + TE;
    // lifetime-based reuse
    float* ab   = xt;        // attention out (xt dead after Z gemm)
    float* x1   = Qb;        // after attention, Q dead
    float* h1   = Kb;
    float* h2   = Vb;
    float* h3   = Zb;        // Z dead after x1
    float* x2   = xt + TE;   // second slice of xt region
    float* outm = Kb;        // h1 dead after h2 gemm

    const int M = B_ * T_;   // 24576

    // 1. gather
    {
        size_t total = (size_t)B_ * T_ * C_ * V_;
        gather_kernel<<<dim3((unsigned)((total + 255) / 256)), dim3(256), 0, stream>>>(sino, idx, xt);
    }
    // 2. Z = xt @ We + be + pos
    gemm_kernel<1><<<dim3((E_ + 63) / 64, (M + 63) / 64), dim3(256), 0, stream>>>(
        xt, We, be, pos, Zb, M, E_, CV_);
    // 3. Q, K, V
    gemm_kernel<0><<<dim3((E_ + 63) / 64, (M + 63) / 64), dim3(256), 0, stream>>>(
        Zb, Wq, nullptr, nullptr, Qb, M, E_, E_);
    gemm_kernel<0><<<dim3((E_ + 63) / 64, (M + 63) / 64), dim3(256), 0, stream>>>(
        Zb, Wk, nullptr, nullptr, Kb, M, E_, E_);
    gemm_kernel<0><<<dim3((E_ + 63) / 64, (M + 63) / 64), dim3(256), 0, stream>>>(
        Zb, Wv, nullptr, nullptr, Vb, M, E_, E_);
    // 4. attention
    attn_kernel<<<dim3(B_ * NH_ * (T_ / 8)), dim3(256), 0, stream>>>(Qb, Kb, Vb, ab);
    // 5. x1 = LN(Z + a)
    ln_kernel<<<dim3(M), dim3(256), 0, stream>>>(Zb, ab, g_att, beta_att, x1);
    // 6-8. MLP
    gemm_kernel<2><<<dim3((E_ + 63) / 64, (M + 63) / 64), dim3(256), 0, stream>>>(
        x1, W1, b1, nullptr, h1, M, E_, E_);
    gemm_kernel<2><<<dim3((E_ + 63) / 64, (M + 63) / 64), dim3(256), 0, stream>>>(
        h1, W2, b2, nullptr, h2, M, E_, E_);
    gemm_kernel<2><<<dim3((E_ + 63) / 64, (M + 63) / 64), dim3(256), 0, stream>>>(
        h2, W3, b3, nullptr, h3, M, E_, E_);
    // 9. x2 = LN(x1 + h3)
    ln_kernel<<<dim3(M), dim3(256), 0, stream>>>(x1, h3, g_mlp, beta_mlp, x2);
    // 10. out = x2 @ Wu + bu
    gemm_kernel<0><<<dim3((V_ + 63) / 64, (M + 63) / 64), dim3(256), 0, stream>>>(
        x2, Wu, bu, nullptr, outm, M, V_, E_);
    // 11. scatter
    {
        size_t total = (size_t)B_ * T_ * V_;
        scatter_kernel<<<dim3((unsigned)((total + 255) / 256)), dim3(256), 0, stream>>>(
            sino, idx, outm, out);
    }
}

// Round 2
// 2350.489 us; speedup vs baseline: 2.0314x; 2.0314x over previous
//
#include <hip/hip_runtime.h>
#include <math.h>

// Problem constants
constexpr int B_  = 96;
constexpr int C_  = 5;
constexpr int H_  = 256;
constexpr int W_  = 256;
constexpr int T_  = 256;
constexpr int V_  = 256;
constexpr int NH_ = 2;
constexpr int DH_ = 156;
constexpr int E_  = NH_ * DH_;   // 312
constexpr int CV_ = C_ * V_;     // 1280

// ---------------------------------------------------------------------------
// 1) Gather: xt[b, t, ch*V + v] = sino[b, ch, r[t,v], c[t,v]]
// ---------------------------------------------------------------------------
__global__ __launch_bounds__(256)
void gather_kernel(const float* __restrict__ sino, const float* __restrict__ idx,
                   float* __restrict__ xt) {
    size_t i = (size_t)blockIdx.x * blockDim.x + threadIdx.x;
    size_t total = (size_t)B_ * T_ * C_ * V_;
    if (i >= total) return;
    int v  = (int)(i % V_);
    size_t j = i / V_;
    int ch = (int)(j % C_);
    j /= C_;
    int t = (int)(j % T_);
    int b = (int)(j / T_);
    int tv = t * V_ + v;
    int r  = (int)idx[(size_t)tv * 3 + 0];
    int cc = (int)idx[(size_t)tv * 3 + 1];
    xt[i] = sino[(((size_t)b * C_ + ch) * H_ + r) * W_ + cc];
}

// ---------------------------------------------------------------------------
// 2) Generic tiled fp32 GEMM: C[M,N] = epi(A[M,K] @ B[K,N] + bias [+ pos])
//    EPI: 0 = bias only (bias may be null), 1 = bias + pos (pos[t, n], t=m%T_),
//         2 = gelu(x + bias)  (exact gelu, erf)
// ---------------------------------------------------------------------------
template <int EPI>
__global__ __launch_bounds__(256)
void gemm_kernel(const float* __restrict__ A, const float* __restrict__ Bm,
                 const float* __restrict__ bias, const float* __restrict__ pos,
                 float* __restrict__ Cout, int M, int N, int K) {
    constexpr int BM = 64, BN = 64, BK = 16;
    __shared__ float As[BK][BM + 1];
    __shared__ float Bs[BK][BN + 1];
    int tid = threadIdx.x;
    int bx = blockIdx.x, by = blockIdx.y;
    int row0 = by * BM, col0 = bx * BN;
    int tx = tid & 15, ty = tid >> 4;
    float acc[4][4] = {};

    for (int k0 = 0; k0 < K; k0 += BK) {
        #pragma unroll
        for (int ld = 0; ld < 4; ++ld) {
            int idx2 = tid + ld * 256;
            int m = idx2 >> 4, k = idx2 & 15;
            int gm = row0 + m, gk = k0 + k;
            As[k][m] = (gm < M && gk < K) ? A[(size_t)gm * K + gk] : 0.f;
        }
        #pragma unroll
        for (int ld = 0; ld < 4; ++ld) {
            int idx2 = tid + ld * 256;
            int k = idx2 >> 6, n = idx2 & 63;
            int gk = k0 + k, gn = col0 + n;
            Bs[k][n] = (gk < K && gn < N) ? Bm[(size_t)gk * N + gn] : 0.f;
        }
        __syncthreads();
        #pragma unroll
        for (int k = 0; k < BK; ++k) {
            float a[4], bb[4];
            #pragma unroll
            for (int i = 0; i < 4; ++i) a[i] = As[k][ty * 4 + i];
            #pragma unroll
            for (int j = 0; j < 4; ++j) bb[j] = Bs[k][tx * 4 + j];
            #pragma unroll
            for (int i = 0; i < 4; ++i)
                #pragma unroll
                for (int j = 0; j < 4; ++j) acc[i][j] += a[i] * bb[j];
        }
        __syncthreads();
    }

    #pragma unroll
    for (int i = 0; i < 4; ++i) {
        int gm = row0 + ty * 4 + i;
        if (gm >= M) continue;
        #pragma unroll
        for (int j = 0; j < 4; ++j) {
            int gn = col0 + tx * 4 + j;
            if (gn >= N) continue;
            float v = acc[i][j];
            if (bias) v += bias[gn];
            if (EPI == 1) v += pos[(size_t)(gm % T_) * N + gn];
            if (EPI == 2) v = 0.5f * v * (1.f + erff(v * 0.70710678118654752f));
            Cout[(size_t)gm * N + gn] = v;
        }
    }
}

// ---------------------------------------------------------------------------
// 3a) Batched score GEMM: S[bh, m, n] = scale * dot(Q[bh,m,:], K[bh,n,:])
//     Q/K stored as (B*T, E) rows; head h at cols [h*DH, (h+1)*DH).
// ---------------------------------------------------------------------------
__global__ __launch_bounds__(256)
void attn_score_kernel(const float* __restrict__ Q, const float* __restrict__ K,
                       float* __restrict__ S) {
    constexpr int BM = 64, BN = 64, BK = 16;
    __shared__ float As[BK][BM + 1];
    __shared__ float Bs[BK][BN + 1];
    int bh = blockIdx.z;
    int h = bh % NH_, b = bh / NH_;
    size_t base = (size_t)b * T_ * E_ + (size_t)h * DH_;
    const float* Qb = Q + base;
    const float* Kb = K + base;
    float* Sb = S + (size_t)bh * T_ * T_;
    int row0 = blockIdx.y * BM, col0 = blockIdx.x * BN;
    int tid = threadIdx.x;
    int tx = tid & 15, ty = tid >> 4;
    float acc[4][4] = {};

    for (int k0 = 0; k0 < DH_; k0 += BK) {
        #pragma unroll
        for (int ld = 0; ld < 4; ++ld) {
            int idx2 = tid + ld * 256;
            int m = idx2 >> 4, k = idx2 & 15;
            int gk = k0 + k;
            As[k][m] = (gk < DH_) ? Qb[(size_t)(row0 + m) * E_ + gk] : 0.f;
        }
        #pragma unroll
        for (int ld = 0; ld < 4; ++ld) {
            int idx2 = tid + ld * 256;
            int n = idx2 >> 4, k = idx2 & 15;
            int gk = k0 + k;
            Bs[k][n] = (gk < DH_) ? Kb[(size_t)(col0 + n) * E_ + gk] : 0.f;
        }
        __syncthreads();
        #pragma unroll
        for (int k = 0; k < BK; ++k) {
            float a[4], bb[4];
            #pragma unroll
            for (int i = 0; i < 4; ++i) a[i] = As[k][ty * 4 + i];
            #pragma unroll
            for (int j = 0; j < 4; ++j) bb[j] = Bs[k][tx * 4 + j];
            #pragma unroll
            for (int i = 0; i < 4; ++i)
                #pragma unroll
                for (int j = 0; j < 4; ++j) acc[i][j] += a[i] * bb[j];
        }
        __syncthreads();
    }

    const float scale = rsqrtf((float)DH_);
    #pragma unroll
    for (int i = 0; i < 4; ++i) {
        int gm = row0 + ty * 4 + i;
        #pragma unroll
        for (int j = 0; j < 4; ++j) {
            int gn = col0 + tx * 4 + j;
            Sb[(size_t)gm * T_ + gn] = acc[i][j] * scale;
        }
    }
}

// ---------------------------------------------------------------------------
// 3b) Row softmax over S rows (in place). One block (256 thr) per row.
// ---------------------------------------------------------------------------
__global__ __launch_bounds__(256)
void softmax_kernel(float* __restrict__ S) {
    size_t row = blockIdx.x;
    int tid = threadIdx.x;
    float* p = S + row * T_;
    __shared__ float red[256];
    float v = p[tid];
    red[tid] = v; __syncthreads();
    for (int off = 128; off > 0; off >>= 1) {
        if (tid < off) red[tid] = fmaxf(red[tid], red[tid + off]);
        __syncthreads();
    }
    float mx = red[0]; __syncthreads();
    float e = expf(v - mx);
    red[tid] = e; __syncthreads();
    for (int off = 128; off > 0; off >>= 1) {
        if (tid < off) red[tid] += red[tid + off];
        __syncthreads();
    }
    p[tid] = e / red[0];
}

// ---------------------------------------------------------------------------
// 3c) Batched AV GEMM: A_out[bh, m, d] = sum_k P[bh,m,k] * V[bh,k,d]
// ---------------------------------------------------------------------------
__global__ __launch_bounds__(256)
void attn_av_kernel(const float* __restrict__ P, const float* __restrict__ Vm,
                    float* __restrict__ Am) {
    constexpr int BM = 64, BN = 64, BK = 16;
    __shared__ float As[BK][BM + 1];
    __shared__ float Bs[BK][BN + 1];
    int bh = blockIdx.z;
    int h = bh % NH_, b = bh / NH_;
    size_t base = (size_t)b * T_ * E_ + (size_t)h * DH_;
    const float* Pb = P + (size_t)bh * T_ * T_;
    const float* Vb = Vm + base;
    float* Ab = Am + base;
    int row0 = blockIdx.y * BM, col0 = blockIdx.x * BN;
    int tid = threadIdx.x;
    int tx = tid & 15, ty = tid >> 4;
    float acc[4][4] = {};

    for (int k0 = 0; k0 < T_; k0 += BK) {
        #pragma unroll
        for (int ld = 0; ld < 4; ++ld) {
            int idx2 = tid + ld * 256;
            int m = idx2 >> 4, k = idx2 & 15;
            As[k][m] = Pb[(size_t)(row0 + m) * T_ + k0 + k];
        }
        #pragma unroll
        for (int ld = 0; ld < 4; ++ld) {
            int idx2 = tid + ld * 256;
            int k = idx2 >> 6, n = idx2 & 63;
            int gn = col0 + n;
            Bs[k][n] = (gn < DH_) ? Vb[(size_t)(k0 + k) * E_ + gn] : 0.f;
        }
        __syncthreads();
        #pragma unroll
        for (int k = 0; k < BK; ++k) {
            float a[4], bb[4];
            #pragma unroll
            for (int i = 0; i < 4; ++i) a[i] = As[k][ty * 4 + i];
            #pragma unroll
            for (int j = 0; j < 4; ++j) bb[j] = Bs[k][tx * 4 + j];
            #pragma unroll
            for (int i = 0; i < 4; ++i)
                #pragma unroll
                for (int j = 0; j < 4; ++j) acc[i][j] += a[i] * bb[j];
        }
        __syncthreads();
    }

    #pragma unroll
    for (int i = 0; i < 4; ++i) {
        int gm = row0 + ty * 4 + i;
        #pragma unroll
        for (int j = 0; j < 4; ++j) {
            int gn = col0 + tx * 4 + j;
            if (gn < DH_) Ab[(size_t)gm * E_ + gn] = acc[i][j];
        }
    }
}

// ---------------------------------------------------------------------------
// 4) LayerNorm of (A + Bi)
// ---------------------------------------------------------------------------
__global__ __launch_bounds__(256)
void ln_kernel(const float* __restrict__ A, const float* __restrict__ Bi,
               const float* __restrict__ g, const float* __restrict__ beta,
               float* __restrict__ Out) {
    int row = blockIdx.x;
    size_t base = (size_t)row * E_;
    int tid = threadIdx.x;
    __shared__ float red[256];
    __shared__ float red2[256];

    float ya = (tid < E_) ? A[base + tid] + Bi[base + tid] : 0.f;
    float yb = (tid + 256 < E_) ? A[base + tid + 256] + Bi[base + tid + 256] : 0.f;
    red[tid]  = ya + yb;
    red2[tid] = ya * ya + yb * yb;
    __syncthreads();
    for (int off = 128; off > 0; off >>= 1) {
        if (tid < off) { red[tid] += red[tid + off]; red2[tid] += red2[tid + off]; }
        __syncthreads();
    }
    float mean = red[0] / E_;
    float var  = red2[0] / E_ - mean * mean;
    float inv  = rsqrtf(var + 1e-5f);
    if (tid < E_)       Out[base + tid]       = (ya - mean) * inv * g[tid] + beta[tid];
    if (tid + 256 < E_) Out[base + tid + 256] = (yb - mean) * inv * g[tid + 256] + beta[tid + 256];
}

// ---------------------------------------------------------------------------
// 5) Scatter + final add
// ---------------------------------------------------------------------------
__global__ __launch_bounds__(256)
void scatter_kernel(const float* __restrict__ sino, const float* __restrict__ idx,
                    const float* __restrict__ outm, float* __restrict__ dout) {
    size_t i = (size_t)blockIdx.x * blockDim.x + threadIdx.x;
    size_t total = (size_t)B_ * T_ * V_;
    if (i >= total) return;
    int tv = (int)(i % ((size_t)T_ * V_));
    int b  = (int)(i / ((size_t)T_ * V_));
    int r  = (int)idx[(size_t)tv * 3 + 0];
    int cc = (int)idx[(size_t)tv * 3 + 1];
    float sc = idx[(size_t)tv * 3 + 2];
    size_t pos = (size_t)r * W_ + cc;
    dout[(size_t)b * H_ * W_ + pos] =
        sino[((size_t)b * C_ + (C_ - 1)) * (size_t)H_ * W_ + pos] + outm[i] * sc;
}

// ---------------------------------------------------------------------------
extern "C" void kernel_launch(void* const* d_in, const int* in_sizes, int n_in,
                              void* d_out, int out_size, void* d_ws, size_t ws_size,
                              hipStream_t stream) {
    const float* sino     = (const float*)d_in[0];
    const float* idx      = (const float*)d_in[1];
    const float* We       = (const float*)d_in[2];
    const float* be       = (const float*)d_in[3];
    const float* pos      = (const float*)d_in[4];
    const float* Wq       = (const float*)d_in[5];
    const float* Wk       = (const float*)d_in[6];
    const float* Wv       = (const float*)d_in[7];
    const float* W1       = (const float*)d_in[8];
    const float* b1       = (const float*)d_in[9];
    const float* W2       = (const float*)d_in[10];
    const float* b2       = (const float*)d_in[11];
    const float* W3       = (const float*)d_in[12];
    const float* b3       = (const float*)d_in[13];
    const float* g_att    = (const float*)d_in[14];
    const float* beta_att = (const float*)d_in[15];
    const float* g_mlp    = (const float*)d_in[16];
    const float* beta_mlp = (const float*)d_in[17];
    const float* Wu       = (const float*)d_in[18];
    const float* bu       = (const float*)d_in[19];
    float* out = (float*)d_out;
    float* ws  = (float*)d_ws;

    const size_t XT_SZ = (size_t)B_ * T_ * CV_;   // 31,457,280
    const size_t TE    = (size_t)B_ * T_ * E_;    //  7,667,712

    float* xt = ws;
    float* Zb = ws + XT_SZ;
    float* Qb = Zb + TE;
    float* Kb = Qb + TE;
    float* Vb = Kb + TE;
    // lifetime-based reuse
    float* ab   = xt;          // attention out (xt dead after Z gemm)
    float* x2   = xt + TE;     // second LN output
    float* Sb   = xt + 2 * TE; // scores: 192*256*256 = 12.58M floats, fits
    float* x1   = Qb;          // after attention, Q dead
    float* h1   = Kb;
    float* h2   = Vb;
    float* h3   = Zb;          // Z dead after x1
    float* outm = Kb;          // h1 dead after h2 gemm

    const int M = B_ * T_;   // 24576

    // 1. gather
    {
        size_t total = (size_t)B_ * T_ * C_ * V_;
        gather_kernel<<<dim3((unsigned)((total + 255) / 256)), dim3(256), 0, stream>>>(sino, idx, xt);
    }
    // 2. Z = xt @ We + be + pos
    gemm_kernel<1><<<dim3((E_ + 63) / 64, (M + 63) / 64), dim3(256), 0, stream>>>(
        xt, We, be, pos, Zb, M, E_, CV_);
    // 3. Q, K, V
    gemm_kernel<0><<<dim3((E_ + 63) / 64, (M + 63) / 64), dim3(256), 0, stream>>>(
        Zb, Wq, nullptr, nullptr, Qb, M, E_, E_);
    gemm_kernel<0><<<dim3((E_ + 63) / 64, (M + 63) / 64), dim3(256), 0, stream>>>(
        Zb, Wk, nullptr, nullptr, Kb, M, E_, E_);
    gemm_kernel<0><<<dim3((E_ + 63) / 64, (M + 63) / 64), dim3(256), 0, stream>>>(
        Zb, Wv, nullptr, nullptr, Vb, M, E_, E_);
    // 4. attention: S = scale*Q@K^T ; softmax ; A = P@V
    attn_score_kernel<<<dim3(T_ / 64, T_ / 64, B_ * NH_), dim3(256), 0, stream>>>(Qb, Kb, Sb);
    softmax_kernel<<<dim3(B_ * NH_ * T_), dim3(256), 0, stream>>>(Sb);
    attn_av_kernel<<<dim3((DH_ + 63) / 64, T_ / 64, B_ * NH_), dim3(256), 0, stream>>>(Sb, Vb, ab);
    // 5. x1 = LN(Z + a)
    ln_kernel<<<dim3(M), dim3(256), 0, stream>>>(Zb, ab, g_att, beta_att, x1);
    // 6-8. MLP
    gemm_kernel<2><<<dim3((E_ + 63) / 64, (M + 63) / 64), dim3(256), 0, stream>>>(
        x1, W1, b1, nullptr, h1, M, E_, E_);
    gemm_kernel<2><<<dim3((E_ + 63) / 64, (M + 63) / 64), dim3(256), 0, stream>>>(
        h1, W2, b2, nullptr, h2, M, E_, E_);
    gemm_kernel<2><<<dim3((E_ + 63) / 64, (M + 63) / 64), dim3(256), 0, stream>>>(
        h2, W3, b3, nullptr, h3, M, E_, E_);
    // 9. x2 = LN(x1 + h3)
    ln_kernel<<<dim3(M), dim3(256), 0, stream>>>(x1, h3, g_mlp, beta_mlp, x2);
    // 10. out = x2 @ Wu + bu
    gemm_kernel<0><<<dim3((V_ + 63) / 64, (M + 63) / 64), dim3(256), 0, stream>>>(
        x2, Wu, bu, nullptr, outm, M, V_, E_);
    // 11. scatter
    {
        size_t total = (size_t)B_ * T_ * V_;
        scatter_kernel<<<dim3((unsigned)((total + 255) / 256)), dim3(256), 0, stream>>>(
            sino, idx, outm, out);
    }
}

// Round 5
// 894.574 us; speedup vs baseline: 5.3374x; 2.6275x over previous
//
#include <hip/hip_runtime.h>
#include <math.h>

// Problem constants
constexpr int B_  = 96;
constexpr int T_  = 256;
constexpr int V_  = 256;
constexpr int C_  = 5;
constexpr int H_  = 256;
constexpr int W_  = 256;
constexpr int NH_ = 2;
constexpr int DH_ = 156;
constexpr int E_  = 312;
constexpr int EP_ = 320;   // padded E
constexpr int DHP_ = 160;  // padded DH
constexpr int CV_ = 1280;
constexpr int M_  = B_ * T_;  // 24576

typedef short short8 __attribute__((ext_vector_type(8)));
typedef float f32x4 __attribute__((ext_vector_type(4)));

__device__ inline short f2bf(float f) {
    unsigned u = __builtin_bit_cast(unsigned, f);
    u = (u + 0x7fff + ((u >> 16) & 1)) >> 16;
    return (short)u;
}

__device__ inline void gld16(const void* g, void* l) {
    __builtin_amdgcn_global_load_lds(
        (const __attribute__((address_space(1))) unsigned*)g,
        (__attribute__((address_space(3))) unsigned*)l, 16, 0, 0);
}

// ---------------------------------------------------------------------------
// Gather -> bf16 xt [M][1280]
// ---------------------------------------------------------------------------
__global__ __launch_bounds__(256)
void gather_kernel(const float* __restrict__ sino, const float* __restrict__ idx,
                   short* __restrict__ xt) {
    size_t i = (size_t)blockIdx.x * 256 + threadIdx.x;
    size_t total = (size_t)M_ * CV_;
    if (i >= total) return;
    int v  = (int)(i % V_);
    size_t j = i / V_;
    int ch = (int)(j % C_);
    j /= C_;
    int t = (int)(j % T_);
    int b = (int)(j / T_);
    int tv = t * V_ + v;
    int r  = (int)idx[(size_t)tv * 3 + 0];
    int cc = (int)idx[(size_t)tv * 3 + 1];
    xt[i] = f2bf(sino[(((size_t)b * C_ + ch) * H_ + r) * W_ + cc]);
}

// ---------------------------------------------------------------------------
// Weight convert+transpose: Wt[n][k] (bf16, [NP][KP], zero-padded)
// from W[k][n] fp32 [Ks][Ns]
// ---------------------------------------------------------------------------
__global__ __launch_bounds__(256)
void wconv_kernel(const float* __restrict__ Wsrc, short* __restrict__ Wt,
                  int Ks, int Ns, int KP, int NP) {
    int idx = blockIdx.x * 256 + threadIdx.x;
    if (idx >= NP * KP) return;
    int n = idx / KP, k = idx - n * KP;
    Wt[idx] = (n < Ns && k < Ks) ? f2bf(Wsrc[(size_t)k * Ns + n]) : (short)0;
}

// ---------------------------------------------------------------------------
// Zero kernel (float4 granularity, grid-stride)
// ---------------------------------------------------------------------------
__global__ __launch_bounds__(256)
void zero_kernel(float4* __restrict__ p, size_t n4) {
    size_t i = (size_t)blockIdx.x * 256 + threadIdx.x;
    size_t stride = (size_t)gridDim.x * 256;
    float4 z; z.x = z.y = z.z = z.w = 0.f;
    for (; i < n4; i += stride) p[i] = z;
}

// ---------------------------------------------------------------------------
// MFMA GEMM: C = A[M,K](bf16) @ Bt[N,K]^T(bf16), per-EPI epilogue.
// Block: 128 threads = 2 waves. Tile BM=128 (wave: 64 rows), BN=64. BK=32.
// ---------------------------------------------------------------------------
#define EPI_EMBED    0
#define EPI_QK       1
#define EPI_VT       2
#define EPI_SCORE    3
#define EPI_AV       4
#define EPI_GELU_BF  5
#define EPI_GELU_F32 6
#define EPI_OUT      7

template <int EPI>
__global__ __launch_bounds__(128)
void mgemm(const short* __restrict__ Aall, const short* __restrict__ Ball,
           const float* __restrict__ bias, const float* __restrict__ pos,
           float* __restrict__ Of, short* __restrict__ Ob,
           int K, int strideA, int strideB) {
    __shared__ __align__(16) char smem[24576];   // 2 bufs x (8KB A + 4KB B)
    const int tid = threadIdx.x;
    const int wv = tid >> 6, ln = tid & 63;
    const int lr = ln & 15, lq = ln >> 4;
    const int z = blockIdx.z;

    const short* A;
    const short* Bt;
    if (EPI == EPI_SCORE)      { A = Aall + (size_t)z * 256 * DHP_; Bt = Ball + (size_t)z * 256 * DHP_; }
    else if (EPI == EPI_AV)    { A = Aall + (size_t)z * 256 * 256;  Bt = Ball + (size_t)z * 192 * 256; }
    else                       { A = Aall; Bt = Ball; }

    const int rm0 = blockIdx.y * 128;
    const int n0  = blockIdx.x * 64;
    const char* Abase = (const char*)(A + (size_t)rm0 * strideA);
    const char* Bbase = (const char*)(Bt + (size_t)n0 * strideB);
    const size_t sA = (size_t)strideA * 2, sB = (size_t)strideB * 2;

    f32x4 acc[4][4];
    #pragma unroll
    for (int mi = 0; mi < 4; ++mi)
        #pragma unroll
        for (int ni = 0; ni < 4; ++ni) acc[mi][ni] = {0.f, 0.f, 0.f, 0.f};

    const int KT = K >> 5;

    auto stage = [&](int buf, int kt) {
        const char* ab = Abase + (size_t)kt * 64;
        char* la = smem + buf * 12288;
        #pragma unroll
        for (int c = 0; c < 4; ++c) {
            int p = wv * 4096 + c * 1024 + ln * 16;
            int r = p >> 6;
            int cc = (p & 63) ^ (((p >> 7) & 3) << 4);
            gld16(ab + (size_t)r * sA + cc, la + wv * 4096 + c * 1024);
        }
        const char* bb = Bbase + (size_t)kt * 64;
        char* lb = smem + buf * 12288 + 8192;
        #pragma unroll
        for (int c = 0; c < 2; ++c) {
            int p = wv * 2048 + c * 1024 + ln * 16;
            int r = p >> 6;
            int cc = (p & 63) ^ (((p >> 7) & 3) << 4);
            gld16(bb + (size_t)r * sB + cc, lb + wv * 2048 + c * 1024);
        }
    };

    stage(0, 0);
    for (int kt = 0; kt < KT; ++kt) {
        __syncthreads();                   // drains vmcnt -> buf[kt&1] ready
        if (kt + 1 < KT) stage((kt + 1) & 1, kt + 1);
        const char* la = smem + (kt & 1) * 12288;
        const char* lb = la + 8192;
        short8 af[4], bfv[4];
        #pragma unroll
        for (int mi = 0; mi < 4; ++mi) {
            int r = wv * 64 + mi * 16 + lr;
            af[mi] = *(const short8*)(la + r * 64 + ((lq * 16) ^ (((r >> 1) & 3) << 4)));
        }
        #pragma unroll
        for (int ni = 0; ni < 4; ++ni) {
            int n = ni * 16 + lr;
            bfv[ni] = *(const short8*)(lb + n * 64 + ((lq * 16) ^ (((n >> 1) & 3) << 4)));
        }
        #pragma unroll
        for (int mi = 0; mi < 4; ++mi)
            #pragma unroll
            for (int ni = 0; ni < 4; ++ni)
                acc[mi][ni] = __builtin_amdgcn_mfma_f32_16x16x32_bf16(
                    af[mi], bfv[ni], acc[mi][ni], 0, 0, 0);
    }

    // Epilogue. D mapping: row = lq*4+i, col = lr (within 16x16 fragment).
    #pragma unroll
    for (int mi = 0; mi < 4; ++mi) {
        #pragma unroll
        for (int i = 0; i < 4; ++i) {
            int gm = rm0 + wv * 64 + mi * 16 + lq * 4 + i;
            #pragma unroll
            for (int ni = 0; ni < 4; ++ni) {
                int gn = n0 + ni * 16 + lr;
                float v = acc[mi][ni][i];
                if (EPI == EPI_EMBED) {
                    if (gn < E_) v += bias[gn] + pos[(size_t)(gm & 255) * E_ + gn];
                    else v = 0.f;
                    Of[(size_t)gm * EP_ + gn] = v;
                    Ob[(size_t)gm * EP_ + gn] = f2bf(v);
                } else if (EPI == EPI_QK) {
                    if (gn < E_) {
                        int h = gn >= DH_;
                        int d = gn - h * DH_;
                        Ob[(((size_t)(gm >> 8) * NH_ + h) * 256 + (gm & 255)) * DHP_ + d] = f2bf(v);
                    }
                } else if (EPI == EPI_VT) {
                    if (gn < E_) {
                        int h = gn >= DH_;
                        int d = gn - h * DH_;
                        Ob[(((size_t)(gm >> 8) * NH_ + h) * 192 + d) * 256 + (gm & 255)] = f2bf(v);
                    }
                } else if (EPI == EPI_SCORE) {
                    Of[((size_t)z * 256 + gm) * 256 + gn] = v * 0.08006407690254357f;
                } else if (EPI == EPI_AV) {
                    if (gn < DH_) {
                        int b = z >> 1, h = z & 1;
                        Of[((size_t)b * 256 + gm) * EP_ + h * DH_ + gn] = v;
                    }
                } else if (EPI == EPI_GELU_BF) {
                    float bi = (gn < E_) ? bias[gn] : 0.f;
                    v += bi;
                    v = 0.5f * v * (1.f + erff(v * 0.70710678118654752f));
                    if (gn >= E_) v = 0.f;
                    Ob[(size_t)gm * EP_ + gn] = f2bf(v);
                } else if (EPI == EPI_GELU_F32) {
                    float bi = (gn < E_) ? bias[gn] : 0.f;
                    v += bi;
                    v = 0.5f * v * (1.f + erff(v * 0.70710678118654752f));
                    if (gn >= E_) v = 0.f;
                    Of[(size_t)gm * EP_ + gn] = v;
                } else if (EPI == EPI_OUT) {
                    v += bias[gn];
                    Of[(size_t)gm * 256 + gn] = v;
                }
            }
        }
    }
}

// ---------------------------------------------------------------------------
// Softmax rows of S (fp32 [rows][256]) -> bf16 P
// ---------------------------------------------------------------------------
__global__ __launch_bounds__(256)
void softmax_bf(const float* __restrict__ S, short* __restrict__ P) {
    size_t row = blockIdx.x;
    int tid = threadIdx.x;
    const float* p = S + row * 256;
    __shared__ float red[256];
    float v = p[tid];
    red[tid] = v; __syncthreads();
    for (int off = 128; off > 0; off >>= 1) {
        if (tid < off) red[tid] = fmaxf(red[tid], red[tid + off]);
        __syncthreads();
    }
    float mx = red[0]; __syncthreads();
    float e = expf(v - mx);
    red[tid] = e; __syncthreads();
    for (int off = 128; off > 0; off >>= 1) {
        if (tid < off) red[tid] += red[tid + off];
        __syncthreads();
    }
    P[row * 256 + tid] = f2bf(e / red[0]);
}

// ---------------------------------------------------------------------------
// LayerNorm of (A + Bi), fp32 in (stride 320, 312 real cols),
// bf16 out (stride 320, zero pads) + optional fp32 out
// ---------------------------------------------------------------------------
template <bool DUAL>
__global__ __launch_bounds__(256)
void ln_kernel(const float* __restrict__ A, const float* __restrict__ Bi,
               const float* __restrict__ g, const float* __restrict__ beta,
               short* __restrict__ Outb, float* __restrict__ Outf) {
    int row = blockIdx.x;
    size_t base = (size_t)row * EP_;
    int tid = threadIdx.x;
    __shared__ float red[256];
    __shared__ float red2[256];

    float ya = A[base + tid] + Bi[base + tid];
    int t2 = tid + 256;
    float yb = (t2 < E_) ? A[base + t2] + Bi[base + t2] : 0.f;
    red[tid]  = ya + yb;
    red2[tid] = ya * ya + yb * yb;
    __syncthreads();
    for (int off = 128; off > 0; off >>= 1) {
        if (tid < off) { red[tid] += red[tid + off]; red2[tid] += red2[tid + off]; }
        __syncthreads();
    }
    float mean = red[0] / (float)E_;
    float var  = red2[0] / (float)E_ - mean * mean;
    float inv  = rsqrtf(var + 1e-5f);
    float oa = (ya - mean) * inv * g[tid] + beta[tid];
    Outb[base + tid] = f2bf(oa);
    if (DUAL) Outf[base + tid] = oa;
    if (t2 < E_) {
        float ob = (yb - mean) * inv * g[t2] + beta[t2];
        Outb[base + t2] = f2bf(ob);
        if (DUAL) Outf[base + t2] = ob;
    } else if (t2 < EP_) {
        Outb[base + t2] = 0;
        if (DUAL) Outf[base + t2] = 0.f;
    }
}

// ---------------------------------------------------------------------------
// Scatter + final add
// ---------------------------------------------------------------------------
__global__ __launch_bounds__(256)
void scatter_kernel(const float* __restrict__ sino, const float* __restrict__ idx,
                    const float* __restrict__ outm, float* __restrict__ dout) {
    size_t i = (size_t)blockIdx.x * 256 + threadIdx.x;
    size_t total = (size_t)B_ * T_ * V_;
    if (i >= total) return;
    int tv = (int)(i % ((size_t)T_ * V_));
    int b  = (int)(i / ((size_t)T_ * V_));
    int r  = (int)idx[(size_t)tv * 3 + 0];
    int cc = (int)idx[(size_t)tv * 3 + 1];
    float sc = idx[(size_t)tv * 3 + 2];
    size_t pos = (size_t)r * W_ + cc;
    dout[(size_t)b * H_ * W_ + pos] =
        sino[((size_t)b * C_ + (C_ - 1)) * (size_t)H_ * W_ + pos] + outm[i] * sc;
}

// ---------------------------------------------------------------------------
extern "C" void kernel_launch(void* const* d_in, const int* in_sizes, int n_in,
                              void* d_out, int out_size, void* d_ws, size_t ws_size,
                              hipStream_t stream) {
    const float* sino     = (const float*)d_in[0];
    const float* idx      = (const float*)d_in[1];
    const float* We       = (const float*)d_in[2];
    const float* be       = (const float*)d_in[3];
    const float* pos      = (const float*)d_in[4];
    const float* Wq       = (const float*)d_in[5];
    const float* Wk       = (const float*)d_in[6];
    const float* Wv       = (const float*)d_in[7];
    const float* W1       = (const float*)d_in[8];
    const float* b1       = (const float*)d_in[9];
    const float* W2       = (const float*)d_in[10];
    const float* b2       = (const float*)d_in[11];
    const float* W3       = (const float*)d_in[12];
    const float* b3       = (const float*)d_in[13];
    const float* g_att    = (const float*)d_in[14];
    const float* beta_att = (const float*)d_in[15];
    const float* g_mlp    = (const float*)d_in[16];
    const float* beta_mlp = (const float*)d_in[17];
    const float* Wu       = (const float*)d_in[18];
    const float* bu       = (const float*)d_in[19];
    float* out = (float*)d_out;
    char* w = (char*)d_ws;

    // Region layout (bytes), lifetime-based reuse
    const size_t oA = 0;                      // 62,914,560: xt_bf -> S_f32 -> h3_f32
    const size_t oB = oA + 62914560;          // 31,457,280: Z_f32 -> h1_bf
    const size_t oC = oB + 31457280;          // 25,165,824: Z_bf -> P_bf
    const size_t oD = oC + 25165824;          // 15,728,640: Qh -> x1_bf
    const size_t oE = oD + 15728640;          // 15,728,640: Kh -> h2_bf
    const size_t oF = oE + 15728640;          // 31,457,280: Vt(18.9M) -> x1_f32
    const size_t oG = oF + 31457280;          // 31,457,280: ab_f32 -> x2_bf
    const size_t oH = oG + 31457280;          // 25,165,824: outm
    const size_t oW = oH + 25165824;          // weights

    short* xt_bf = (short*)(w + oA);
    float* Sf    = (float*)(w + oA);
    float* h3f   = (float*)(w + oA);
    float* Zf    = (float*)(w + oB);
    short* h1b   = (short*)(w + oB);
    short* Zb    = (short*)(w + oC);
    short* Pb    = (short*)(w + oC);
    short* Qh    = (short*)(w + oD);
    short* x1b   = (short*)(w + oD);
    short* Kh    = (short*)(w + oE);
    short* h2b   = (short*)(w + oE);
    short* Vt    = (short*)(w + oF);
    float* x1f   = (float*)(w + oF);
    float* abf   = (float*)(w + oG);
    short* x2b   = (short*)(w + oG);
    float* outm  = (float*)(w + oH);
    short* We_t  = (short*)(w + oW);
    short* Wq_t  = We_t + 409600;
    short* Wk_t  = Wq_t + 102400;
    short* Wv_t  = Wk_t + 102400;
    short* W1_t  = Wv_t + 102400;
    short* W2_t  = W1_t + 102400;
    short* W3_t  = W2_t + 102400;
    short* Wu_t  = W3_t + 102400;

    // 1. gather -> bf16 xt
    gather_kernel<<<dim3((M_ * CV_) / 256), dim3(256), 0, stream>>>(sino, idx, xt_bf);

    // 2. weight converts
    wconv_kernel<<<dim3(1600), dim3(256), 0, stream>>>(We, We_t, 1280, E_, 1280, EP_);
    wconv_kernel<<<dim3(400), dim3(256), 0, stream>>>(Wq, Wq_t, E_, E_, EP_, EP_);
    wconv_kernel<<<dim3(400), dim3(256), 0, stream>>>(Wk, Wk_t, E_, E_, EP_, EP_);
    wconv_kernel<<<dim3(400), dim3(256), 0, stream>>>(Wv, Wv_t, E_, E_, EP_, EP_);
    wconv_kernel<<<dim3(400), dim3(256), 0, stream>>>(W1, W1_t, E_, E_, EP_, EP_);
    wconv_kernel<<<dim3(400), dim3(256), 0, stream>>>(W2, W2_t, E_, E_, EP_, EP_);
    wconv_kernel<<<dim3(400), dim3(256), 0, stream>>>(W3, W3_t, E_, E_, EP_, EP_);
    wconv_kernel<<<dim3(320), dim3(256), 0, stream>>>(Wu, Wu_t, E_, 256, EP_, 256);

    // 3. zero Qh/Kh/Vt (pads must be 0; ws is poisoned every call)
    zero_kernel<<<dim3(4096), dim3(256), 0, stream>>>((float4*)(w + oD), 50331648 / 16);

    // 4. Z = xt @ We + be + pos  (fp32 + bf16)
    mgemm<EPI_EMBED><<<dim3(EP_ / 64, M_ / 128), dim3(128), 0, stream>>>(
        xt_bf, We_t, be, pos, Zf, Zb, CV_, CV_, CV_);

    // 5. Q, K (head layout), V (transposed head layout)
    mgemm<EPI_QK><<<dim3(EP_ / 64, M_ / 128), dim3(128), 0, stream>>>(
        Zb, Wq_t, nullptr, nullptr, nullptr, Qh, EP_, EP_, EP_);
    mgemm<EPI_QK><<<dim3(EP_ / 64, M_ / 128), dim3(128), 0, stream>>>(
        Zb, Wk_t, nullptr, nullptr, nullptr, Kh, EP_, EP_, EP_);
    mgemm<EPI_VT><<<dim3(EP_ / 64, M_ / 128), dim3(128), 0, stream>>>(
        Zb, Wv_t, nullptr, nullptr, nullptr, Vt, EP_, EP_, EP_);

    // 6. attention
    mgemm<EPI_SCORE><<<dim3(4, 2, B_ * NH_), dim3(128), 0, stream>>>(
        Qh, Kh, nullptr, nullptr, Sf, nullptr, DHP_, DHP_, DHP_);
    softmax_bf<<<dim3(B_ * NH_ * 256), dim3(256), 0, stream>>>(Sf, Pb);
    mgemm<EPI_AV><<<dim3(3, 2, B_ * NH_), dim3(128), 0, stream>>>(
        Pb, Vt, nullptr, nullptr, abf, nullptr, 256, 256, 256);

    // 7. x1 = LN(Z + a)  (fp32 + bf16)
    ln_kernel<true><<<dim3(M_), dim3(256), 0, stream>>>(Zf, abf, g_att, beta_att, x1b, x1f);

    // 8. MLP
    mgemm<EPI_GELU_BF><<<dim3(EP_ / 64, M_ / 128), dim3(128), 0, stream>>>(
        x1b, W1_t, b1, nullptr, nullptr, h1b, EP_, EP_, EP_);
    mgemm<EPI_GELU_BF><<<dim3(EP_ / 64, M_ / 128), dim3(128), 0, stream>>>(
        h1b, W2_t, b2, nullptr, nullptr, h2b, EP_, EP_, EP_);
    mgemm<EPI_GELU_F32><<<dim3(EP_ / 64, M_ / 128), dim3(128), 0, stream>>>(
        h2b, W3_t, b3, nullptr, h3f, nullptr, EP_, EP_, EP_);

    // 9. x2 = LN(x1 + h)  (bf16 only)
    ln_kernel<false><<<dim3(M_), dim3(256), 0, stream>>>(x1f, h3f, g_mlp, beta_mlp, x2b, nullptr);

    // 10. out = x2 @ Wu + bu (fp32)
    mgemm<EPI_OUT><<<dim3(256 / 64, M_ / 128), dim3(128), 0, stream>>>(
        x2b, Wu_t, bu, nullptr, outm, nullptr, EP_, EP_, EP_);

    // 11. scatter
    scatter_kernel<<<dim3((B_ * T_ * V_) / 256), dim3(256), 0, stream>>>(sino, idx, outm, out);
}

// Round 6
// 850.455 us; speedup vs baseline: 5.6143x; 1.0519x over previous
//
#include <hip/hip_runtime.h>
#include <math.h>

// Problem constants
constexpr int B_  = 96;
constexpr int T_  = 256;
constexpr int V_  = 256;
constexpr int C_  = 5;
constexpr int H_  = 256;
constexpr int W_  = 256;
constexpr int NH_ = 2;
constexpr int DH_ = 156;
constexpr int E_  = 312;
constexpr int EP_ = 320;   // padded E
constexpr int DHP_ = 160;  // padded DH
constexpr int CV_ = 1280;
constexpr int M_  = B_ * T_;  // 24576

typedef short short8 __attribute__((ext_vector_type(8)));
typedef float f32x4 __attribute__((ext_vector_type(4)));

__device__ inline short f2bf(float f) {
    unsigned u = __builtin_bit_cast(unsigned, f);
    u = (u + 0x7fff + ((u >> 16) & 1)) >> 16;
    return (short)u;
}

__device__ inline void gld16(const void* g, void* l) {
    __builtin_amdgcn_global_load_lds(
        (const __attribute__((address_space(1))) unsigned*)g,
        (__attribute__((address_space(3))) unsigned*)l, 16, 0, 0);
}

// ---------------------------------------------------------------------------
// Gather -> bf16 xt [M][1280], XCD-pinned plane-major order.
// plane = (b, ch): 480 planes of 256 KB; 16 blocks/plane; plane%8 == XCD
// (bid%8 round-robin dispatch) so each plane's 16 line-reuses hit that
// XCD's L2. 60 planes/XCD processed back-to-back.
// ---------------------------------------------------------------------------
__global__ __launch_bounds__(256)
void gather_kernel(const float* __restrict__ sino, const float* __restrict__ idx,
                   short* __restrict__ xt) {
    int bid = blockIdx.x;
    int xcd = bid & 7, slot = bid >> 3;
    int sub = slot & 15, pidx = slot >> 4;
    int plane = pidx * 8 + xcd;          // [0, 480)
    int b = plane / C_, ch = plane - b * C_;
    const float* sp = sino + ((size_t)b * C_ + ch) * (H_ * W_);
    int tid = threadIdx.x;
    #pragma unroll
    for (int tt = 0; tt < 16; ++tt) {
        int t = sub * 16 + tt;
        int tv = t * 256 + tid;
        int r  = (int)idx[(size_t)tv * 3 + 0];
        int cc = (int)idx[(size_t)tv * 3 + 1];
        xt[(((size_t)b * T_ + t) * C_ + ch) * V_ + tid] = f2bf(sp[r * W_ + cc]);
    }
}

// ---------------------------------------------------------------------------
// Weight convert+transpose: Wt[n][k] (bf16, [NP][KP], zero-padded)
// from W[k][n] fp32 [Ks][Ns]
// ---------------------------------------------------------------------------
__global__ __launch_bounds__(256)
void wconv_kernel(const float* __restrict__ Wsrc, short* __restrict__ Wt,
                  int Ks, int Ns, int KP, int NP) {
    int idx = blockIdx.x * 256 + threadIdx.x;
    if (idx >= NP * KP) return;
    int n = idx / KP, k = idx - n * KP;
    Wt[idx] = (n < Ns && k < Ks) ? f2bf(Wsrc[(size_t)k * Ns + n]) : (short)0;
}

// ---------------------------------------------------------------------------
// Zero kernel (float4 granularity, grid-stride)
// ---------------------------------------------------------------------------
__global__ __launch_bounds__(256)
void zero_kernel(float4* __restrict__ p, size_t n4) {
    size_t i = (size_t)blockIdx.x * 256 + threadIdx.x;
    size_t stride = (size_t)gridDim.x * 256;
    float4 z; z.x = z.y = z.z = z.w = 0.f;
    for (; i < n4; i += stride) p[i] = z;
}

// ---------------------------------------------------------------------------
// MFMA GEMM: C = A[M,K](bf16) @ Bt[N,K]^T(bf16), per-EPI epilogue.
// Block: 128 threads = 2 waves. Tile BM=128 (wave: 64 rows), BN=64. BK=32.
// ---------------------------------------------------------------------------
#define EPI_EMBED    0
#define EPI_QK       1
#define EPI_VT       2
#define EPI_SCORE    3
#define EPI_AV       4
#define EPI_GELU_BF  5
#define EPI_GELU_F32 6
#define EPI_OUT      7

template <int EPI>
__global__ __launch_bounds__(128)
void mgemm(const short* __restrict__ Aall, const short* __restrict__ Ball,
           const float* __restrict__ bias, const float* __restrict__ pos,
           float* __restrict__ Of, short* __restrict__ Ob,
           int K, int strideA, int strideB) {
    __shared__ __align__(16) char smem[24576];   // 2 bufs x (8KB A + 4KB B)
    const int tid = threadIdx.x;
    const int wv = tid >> 6, ln = tid & 63;
    const int lr = ln & 15, lq = ln >> 4;
    const int z = blockIdx.z;

    const short* A;
    const short* Bt;
    if (EPI == EPI_SCORE)      { A = Aall + (size_t)z * 256 * DHP_; Bt = Ball + (size_t)z * 256 * DHP_; }
    else if (EPI == EPI_AV)    { A = Aall + (size_t)z * 256 * 256;  Bt = Ball + (size_t)z * 192 * 256; }
    else                       { A = Aall; Bt = Ball; }

    const int rm0 = blockIdx.y * 128;
    const int n0  = blockIdx.x * 64;
    const char* Abase = (const char*)(A + (size_t)rm0 * strideA);
    const char* Bbase = (const char*)(Bt + (size_t)n0 * strideB);
    const size_t sA = (size_t)strideA * 2, sB = (size_t)strideB * 2;

    f32x4 acc[4][4];
    #pragma unroll
    for (int mi = 0; mi < 4; ++mi)
        #pragma unroll
        for (int ni = 0; ni < 4; ++ni) acc[mi][ni] = {0.f, 0.f, 0.f, 0.f};

    const int KT = K >> 5;

    auto stage = [&](int buf, int kt) {
        const char* ab = Abase + (size_t)kt * 64;
        char* la = smem + buf * 12288;
        #pragma unroll
        for (int c = 0; c < 4; ++c) {
            int p = wv * 4096 + c * 1024 + ln * 16;
            int r = p >> 6;
            int cc = (p & 63) ^ (((p >> 7) & 3) << 4);
            gld16(ab + (size_t)r * sA + cc, la + wv * 4096 + c * 1024);
        }
        const char* bb = Bbase + (size_t)kt * 64;
        char* lb = smem + buf * 12288 + 8192;
        #pragma unroll
        for (int c = 0; c < 2; ++c) {
            int p = wv * 2048 + c * 1024 + ln * 16;
            int r = p >> 6;
            int cc = (p & 63) ^ (((p >> 7) & 3) << 4);
            gld16(bb + (size_t)r * sB + cc, lb + wv * 2048 + c * 1024);
        }
    };

    stage(0, 0);
    for (int kt = 0; kt < KT; ++kt) {
        __syncthreads();                   // drains vmcnt -> buf[kt&1] ready
        if (kt + 1 < KT) stage((kt + 1) & 1, kt + 1);
        const char* la = smem + (kt & 1) * 12288;
        const char* lb = la + 8192;
        short8 af[4], bfv[4];
        #pragma unroll
        for (int mi = 0; mi < 4; ++mi) {
            int r = wv * 64 + mi * 16 + lr;
            af[mi] = *(const short8*)(la + r * 64 + ((lq * 16) ^ (((r >> 1) & 3) << 4)));
        }
        #pragma unroll
        for (int ni = 0; ni < 4; ++ni) {
            int n = ni * 16 + lr;
            bfv[ni] = *(const short8*)(lb + n * 64 + ((lq * 16) ^ (((n >> 1) & 3) << 4)));
        }
        #pragma unroll
        for (int mi = 0; mi < 4; ++mi)
            #pragma unroll
            for (int ni = 0; ni < 4; ++ni)
                acc[mi][ni] = __builtin_amdgcn_mfma_f32_16x16x32_bf16(
                    af[mi], bfv[ni], acc[mi][ni], 0, 0, 0);
    }

    // Epilogue. D mapping: row = lq*4+i, col = lr (within 16x16 fragment).
    #pragma unroll
    for (int mi = 0; mi < 4; ++mi) {
        #pragma unroll
        for (int i = 0; i < 4; ++i) {
            int gm = rm0 + wv * 64 + mi * 16 + lq * 4 + i;
            #pragma unroll
            for (int ni = 0; ni < 4; ++ni) {
                int gn = n0 + ni * 16 + lr;
                float v = acc[mi][ni][i];
                if (EPI == EPI_EMBED) {
                    if (gn < E_) v += bias[gn] + pos[(size_t)(gm & 255) * E_ + gn];
                    else v = 0.f;
                    Of[(size_t)gm * EP_ + gn] = v;
                    Ob[(size_t)gm * EP_ + gn] = f2bf(v);
                } else if (EPI == EPI_QK) {
                    if (gn < E_) {
                        int h = gn >= DH_;
                        int d = gn - h * DH_;
                        Ob[(((size_t)(gm >> 8) * NH_ + h) * 256 + (gm & 255)) * DHP_ + d] = f2bf(v);
                    }
                } else if (EPI == EPI_VT) {
                    if (gn < E_) {
                        int h = gn >= DH_;
                        int d = gn - h * DH_;
                        Ob[(((size_t)(gm >> 8) * NH_ + h) * 192 + d) * 256 + (gm & 255)] = f2bf(v);
                    }
                } else if (EPI == EPI_SCORE) {
                    Of[((size_t)z * 256 + gm) * 256 + gn] = v * 0.08006407690254357f;
                } else if (EPI == EPI_AV) {
                    if (gn < DH_) {
                        int b = z >> 1, h = z & 1;
                        Of[((size_t)b * 256 + gm) * EP_ + h * DH_ + gn] = v;
                    }
                } else if (EPI == EPI_GELU_BF) {
                    float bi = (gn < E_) ? bias[gn] : 0.f;
                    v += bi;
                    v = 0.5f * v * (1.f + erff(v * 0.70710678118654752f));
                    if (gn >= E_) v = 0.f;
                    Ob[(size_t)gm * EP_ + gn] = f2bf(v);
                } else if (EPI == EPI_GELU_F32) {
                    float bi = (gn < E_) ? bias[gn] : 0.f;
                    v += bi;
                    v = 0.5f * v * (1.f + erff(v * 0.70710678118654752f));
                    if (gn >= E_) v = 0.f;
                    Of[(size_t)gm * EP_ + gn] = v;
                } else if (EPI == EPI_OUT) {
                    v += bias[gn];
                    Of[(size_t)gm * 256 + gn] = v;
                }
            }
        }
    }
}

// ---------------------------------------------------------------------------
// Softmax rows of S (fp32 [rows][256]) -> bf16 P
// ---------------------------------------------------------------------------
__global__ __launch_bounds__(256)
void softmax_bf(const float* __restrict__ S, short* __restrict__ P) {
    size_t row = blockIdx.x;
    int tid = threadIdx.x;
    const float* p = S + row * 256;
    __shared__ float red[256];
    float v = p[tid];
    red[tid] = v; __syncthreads();
    for (int off = 128; off > 0; off >>= 1) {
        if (tid < off) red[tid] = fmaxf(red[tid], red[tid + off]);
        __syncthreads();
    }
    float mx = red[0]; __syncthreads();
    float e = expf(v - mx);
    red[tid] = e; __syncthreads();
    for (int off = 128; off > 0; off >>= 1) {
        if (tid < off) red[tid] += red[tid + off];
        __syncthreads();
    }
    P[row * 256 + tid] = f2bf(e / red[0]);
}

// ---------------------------------------------------------------------------
// LayerNorm of (A + Bi), fp32 in (stride 320, 312 real cols),
// bf16 out (stride 320, zero pads) + optional fp32 out
// ---------------------------------------------------------------------------
template <bool DUAL>
__global__ __launch_bounds__(256)
void ln_kernel(const float* __restrict__ A, const float* __restrict__ Bi,
               const float* __restrict__ g, const float* __restrict__ beta,
               short* __restrict__ Outb, float* __restrict__ Outf) {
    int row = blockIdx.x;
    size_t base = (size_t)row * EP_;
    int tid = threadIdx.x;
    __shared__ float red[256];
    __shared__ float red2[256];

    float ya = A[base + tid] + Bi[base + tid];
    int t2 = tid + 256;
    float yb = (t2 < E_) ? A[base + t2] + Bi[base + t2] : 0.f;
    red[tid]  = ya + yb;
    red2[tid] = ya * ya + yb * yb;
    __syncthreads();
    for (int off = 128; off > 0; off >>= 1) {
        if (tid < off) { red[tid] += red[tid + off]; red2[tid] += red2[tid + off]; }
        __syncthreads();
    }
    float mean = red[0] / (float)E_;
    float var  = red2[0] / (float)E_ - mean * mean;
    float inv  = rsqrtf(var + 1e-5f);
    float oa = (ya - mean) * inv * g[tid] + beta[tid];
    Outb[base + tid] = f2bf(oa);
    if (DUAL) Outf[base + tid] = oa;
    if (t2 < E_) {
        float ob = (yb - mean) * inv * g[t2] + beta[t2];
        Outb[base + t2] = f2bf(ob);
        if (DUAL) Outf[base + t2] = ob;
    } else if (t2 < EP_) {
        Outb[base + t2] = 0;
        if (DUAL) Outf[base + t2] = 0.f;
    }
}

// ---------------------------------------------------------------------------
// Scatter + final add
// ---------------------------------------------------------------------------
__global__ __launch_bounds__(256)
void scatter_kernel(const float* __restrict__ sino, const float* __restrict__ idx,
                    const float* __restrict__ outm, float* __restrict__ dout) {
    size_t i = (size_t)blockIdx.x * 256 + threadIdx.x;
    size_t total = (size_t)B_ * T_ * V_;
    if (i >= total) return;
    int tv = (int)(i % ((size_t)T_ * V_));
    int b  = (int)(i / ((size_t)T_ * V_));
    int r  = (int)idx[(size_t)tv * 3 + 0];
    int cc = (int)idx[(size_t)tv * 3 + 1];
    float sc = idx[(size_t)tv * 3 + 2];
    size_t pos = (size_t)r * W_ + cc;
    dout[(size_t)b * H_ * W_ + pos] =
        sino[((size_t)b * C_ + (C_ - 1)) * (size_t)H_ * W_ + pos] + outm[i] * sc;
}

// ---------------------------------------------------------------------------
extern "C" void kernel_launch(void* const* d_in, const int* in_sizes, int n_in,
                              void* d_out, int out_size, void* d_ws, size_t ws_size,
                              hipStream_t stream) {
    const float* sino     = (const float*)d_in[0];
    const float* idx      = (const float*)d_in[1];
    const float* We       = (const float*)d_in[2];
    const float* be       = (const float*)d_in[3];
    const float* pos      = (const float*)d_in[4];
    const float* Wq       = (const float*)d_in[5];
    const float* Wk       = (const float*)d_in[6];
    const float* Wv       = (const float*)d_in[7];
    const float* W1       = (const float*)d_in[8];
    const float* b1       = (const float*)d_in[9];
    const float* W2       = (const float*)d_in[10];
    const float* b2       = (const float*)d_in[11];
    const float* W3       = (const float*)d_in[12];
    const float* b3       = (const float*)d_in[13];
    const float* g_att    = (const float*)d_in[14];
    const float* beta_att = (const float*)d_in[15];
    const float* g_mlp    = (const float*)d_in[16];
    const float* beta_mlp = (const float*)d_in[17];
    const float* Wu       = (const float*)d_in[18];
    const float* bu       = (const float*)d_in[19];
    float* out = (float*)d_out;
    char* w = (char*)d_ws;

    // Region layout (bytes), lifetime-based reuse
    const size_t oA = 0;                      // 62,914,560: xt_bf -> S_f32 -> h3_f32
    const size_t oB = oA + 62914560;          // 31,457,280: Z_f32 -> h1_bf
    const size_t oC = oB + 31457280;          // 25,165,824: Z_bf -> P_bf
    const size_t oD = oC + 25165824;          // 15,728,640: Qh -> x1_bf
    const size_t oE = oD + 15728640;          // 15,728,640: Kh -> h2_bf
    const size_t oF = oE + 15728640;          // 31,457,280: Vt(18.9M) -> x1_f32
    const size_t oG = oF + 31457280;          // 31,457,280: ab_f32 -> x2_bf
    const size_t oH = oG + 31457280;          // 25,165,824: outm
    const size_t oW = oH + 25165824;          // weights

    short* xt_bf = (short*)(w + oA);
    float* Sf    = (float*)(w + oA);
    float* h3f   = (float*)(w + oA);
    float* Zf    = (float*)(w + oB);
    short* h1b   = (short*)(w + oB);
    short* Zb    = (short*)(w + oC);
    short* Pb    = (short*)(w + oC);
    short* Qh    = (short*)(w + oD);
    short* x1b   = (short*)(w + oD);
    short* Kh    = (short*)(w + oE);
    short* h2b   = (short*)(w + oE);
    short* Vt    = (short*)(w + oF);
    float* x1f   = (float*)(w + oF);
    float* abf   = (float*)(w + oG);
    short* x2b   = (short*)(w + oG);
    float* outm  = (float*)(w + oH);
    short* We_t  = (short*)(w + oW);
    short* Wq_t  = We_t + 409600;
    short* Wk_t  = Wq_t + 102400;
    short* Wv_t  = Wk_t + 102400;
    short* W1_t  = Wv_t + 102400;
    short* W2_t  = W1_t + 102400;
    short* W3_t  = W2_t + 102400;
    short* Wu_t  = W3_t + 102400;

    // 1. gather -> bf16 xt (XCD-pinned plane-major: 480 planes x 16 blocks)
    gather_kernel<<<dim3(7680), dim3(256), 0, stream>>>(sino, idx, xt_bf);

    // 2. weight converts
    wconv_kernel<<<dim3(1600), dim3(256), 0, stream>>>(We, We_t, 1280, E_, 1280, EP_);
    wconv_kernel<<<dim3(400), dim3(256), 0, stream>>>(Wq, Wq_t, E_, E_, EP_, EP_);
    wconv_kernel<<<dim3(400), dim3(256), 0, stream>>>(Wk, Wk_t, E_, E_, EP_, EP_);
    wconv_kernel<<<dim3(400), dim3(256), 0, stream>>>(Wv, Wv_t, E_, E_, EP_, EP_);
    wconv_kernel<<<dim3(400), dim3(256), 0, stream>>>(W1, W1_t, E_, E_, EP_, EP_);
    wconv_kernel<<<dim3(400), dim3(256), 0, stream>>>(W2, W2_t, E_, E_, EP_, EP_);
    wconv_kernel<<<dim3(400), dim3(256), 0, stream>>>(W3, W3_t, E_, E_, EP_, EP_);
    wconv_kernel<<<dim3(320), dim3(256), 0, stream>>>(Wu, Wu_t, E_, 256, EP_, 256);

    // 3. zero Qh/Kh/Vt (pads must be 0; ws is poisoned every call)
    zero_kernel<<<dim3(4096), dim3(256), 0, stream>>>((float4*)(w + oD), 50331648 / 16);

    // 4. Z = xt @ We + be + pos  (fp32 + bf16)
    mgemm<EPI_EMBED><<<dim3(EP_ / 64, M_ / 128), dim3(128), 0, stream>>>(
        xt_bf, We_t, be, pos, Zf, Zb, CV_, CV_, CV_);

    // 5. Q, K (head layout), V (transposed head layout)
    mgemm<EPI_QK><<<dim3(EP_ / 64, M_ / 128), dim3(128), 0, stream>>>(
        Zb, Wq_t, nullptr, nullptr, nullptr, Qh, EP_, EP_, EP_);
    mgemm<EPI_QK><<<dim3(EP_ / 64, M_ / 128), dim3(128), 0, stream>>>(
        Zb, Wk_t, nullptr, nullptr, nullptr, Kh, EP_, EP_, EP_);
    mgemm<EPI_VT><<<dim3(EP_ / 64, M_ / 128), dim3(128), 0, stream>>>(
        Zb, Wv_t, nullptr, nullptr, nullptr, Vt, EP_, EP_, EP_);

    // 6. attention
    mgemm<EPI_SCORE><<<dim3(4, 2, B_ * NH_), dim3(128), 0, stream>>>(
        Qh, Kh, nullptr, nullptr, Sf, nullptr, DHP_, DHP_, DHP_);
    softmax_bf<<<dim3(B_ * NH_ * 256), dim3(256), 0, stream>>>(Sf, Pb);
    mgemm<EPI_AV><<<dim3(3, 2, B_ * NH_), dim3(128), 0, stream>>>(
        Pb, Vt, nullptr, nullptr, abf, nullptr, 256, 256, 256);

    // 7. x1 = LN(Z + a)  (fp32 + bf16)
    ln_kernel<true><<<dim3(M_), dim3(256), 0, stream>>>(Zf, abf, g_att, beta_att, x1b, x1f);

    // 8. MLP
    mgemm<EPI_GELU_BF><<<dim3(EP_ / 64, M_ / 128), dim3(128), 0, stream>>>(
        x1b, W1_t, b1, nullptr, nullptr, h1b, EP_, EP_, EP_);
    mgemm<EPI_GELU_BF><<<dim3(EP_ / 64, M_ / 128), dim3(128), 0, stream>>>(
        h1b, W2_t, b2, nullptr, nullptr, h2b, EP_, EP_, EP_);
    mgemm<EPI_GELU_F32><<<dim3(EP_ / 64, M_ / 128), dim3(128), 0, stream>>>(
        h2b, W3_t, b3, nullptr, h3f, nullptr, EP_, EP_, EP_);

    // 9. x2 = LN(x1 + h)  (bf16 only)
    ln_kernel<false><<<dim3(M_), dim3(256), 0, stream>>>(x1f, h3f, g_mlp, beta_mlp, x2b, nullptr);

    // 10. out = x2 @ Wu + bu (fp32)
    mgemm<EPI_OUT><<<dim3(256 / 64, M_ / 128), dim3(128), 0, stream>>>(
        x2b, Wu_t, bu, nullptr, outm, nullptr, EP_, EP_, EP_);

    // 11. scatter
    scatter_kernel<<<dim3((B_ * T_ * V_) / 256), dim3(256), 0, stream>>>(sino, idx, outm, out);
}

// Round 7
// 796.927 us; speedup vs baseline: 5.9914x; 1.0672x over previous
//
#include <hip/hip_runtime.h>
#include <math.h>

// Problem constants
constexpr int B_  = 96;
constexpr int T_  = 256;
constexpr int V_  = 256;
constexpr int C_  = 5;
constexpr int H_  = 256;
constexpr int W_  = 256;
constexpr int NH_ = 2;
constexpr int DH_ = 156;
constexpr int E_  = 312;
constexpr int EP_ = 320;   // padded E
constexpr int DHP_ = 160;  // padded DH
constexpr int CV_ = 1280;
constexpr int M_  = B_ * T_;  // 24576

typedef short short8 __attribute__((ext_vector_type(8)));
typedef float f32x4 __attribute__((ext_vector_type(4)));

__device__ inline short f2bf(float f) {
    unsigned u = __builtin_bit_cast(unsigned, f);
    u = (u + 0x7fff + ((u >> 16) & 1)) >> 16;
    return (short)u;
}

__device__ inline void gld16(const void* g, void* l) {
    __builtin_amdgcn_global_load_lds(
        (const __attribute__((address_space(1))) unsigned*)g,
        (__attribute__((address_space(3))) unsigned*)l, 16, 0, 0);
}

// ---------------------------------------------------------------------------
// Gather -> bf16 xt [M][1280], XCD-pinned plane-major, 16-deep load ILP.
// Phase 1: 16 (r,c) -> addr regs. Phase 2: 16 divergent loads in flight.
// Phase 3: coalesced bf16 stores.
// ---------------------------------------------------------------------------
__global__ __launch_bounds__(256)
void gather_kernel(const float* __restrict__ sino, const float* __restrict__ idx,
                   short* __restrict__ xt) {
    int bid = blockIdx.x;
    int xcd = bid & 7, slot = bid >> 3;
    int sub = slot & 15, pidx = slot >> 4;
    int plane = pidx * 8 + xcd;          // [0, 480)
    int b = plane / C_, ch = plane - b * C_;
    const float* sp = sino + ((size_t)b * C_ + ch) * (H_ * W_);
    int tid = threadIdx.x;

    int addr[16];
    #pragma unroll
    for (int tt = 0; tt < 16; ++tt) {
        int tv = (sub * 16 + tt) * 256 + tid;
        int r  = (int)idx[(size_t)tv * 3 + 0];
        int cc = (int)idx[(size_t)tv * 3 + 1];
        addr[tt] = r * W_ + cc;
    }
    float pix[16];
    #pragma unroll
    for (int tt = 0; tt < 16; ++tt) pix[tt] = sp[addr[tt]];
    size_t dbase = (((size_t)b * T_ + sub * 16) * C_ + ch) * V_ + tid;
    #pragma unroll
    for (int tt = 0; tt < 16; ++tt)
        xt[dbase + (size_t)tt * (C_ * V_)] = f2bf(pix[tt]);
}

// ---------------------------------------------------------------------------
// Weight convert+transpose: Wt[n][k] (bf16, [NP][KP], zero-padded)
// ---------------------------------------------------------------------------
__global__ __launch_bounds__(256)
void wconv_kernel(const float* __restrict__ Wsrc, short* __restrict__ Wt,
                  int Ks, int Ns, int KP, int NP) {
    int idx = blockIdx.x * 256 + threadIdx.x;
    if (idx >= NP * KP) return;
    int n = idx / KP, k = idx - n * KP;
    Wt[idx] = (n < Ns && k < Ks) ? f2bf(Wsrc[(size_t)k * Ns + n]) : (short)0;
}

// ---------------------------------------------------------------------------
// MFMA GEMM: C = A[M,K](bf16) @ Bt[N,K]^T(bf16), per-EPI epilogue.
// Block: 128 threads = 2 waves. Tile BM=128 (wave: 64 rows), BN=64. BK=32.
// ---------------------------------------------------------------------------
#define EPI_EMBED    0
#define EPI_QK       1
#define EPI_VT       2
#define EPI_AV       4
#define EPI_GELU_BF  5
#define EPI_GELU_F32 6
#define EPI_OUT      7

template <int EPI>
__global__ __launch_bounds__(128)
void mgemm(const short* __restrict__ Aall, const short* __restrict__ Ball,
           const float* __restrict__ bias, const float* __restrict__ pos,
           float* __restrict__ Of, short* __restrict__ Ob,
           int K, int strideA, int strideB) {
    __shared__ __align__(16) char smem[24576];   // 2 bufs x (8KB A + 4KB B)
    const int tid = threadIdx.x;
    const int wv = tid >> 6, ln = tid & 63;
    const int lr = ln & 15, lq = ln >> 4;
    const int z = blockIdx.z;

    const short* A;
    const short* Bt;
    if (EPI == EPI_AV) { A = Aall + (size_t)z * 256 * 256;  Bt = Ball + (size_t)z * 192 * 256; }
    else               { A = Aall; Bt = Ball; }

    const int rm0 = blockIdx.y * 128;
    const int n0  = blockIdx.x * 64;
    const char* Abase = (const char*)(A + (size_t)rm0 * strideA);
    const char* Bbase = (const char*)(Bt + (size_t)n0 * strideB);
    const size_t sA = (size_t)strideA * 2, sB = (size_t)strideB * 2;

    f32x4 acc[4][4];
    #pragma unroll
    for (int mi = 0; mi < 4; ++mi)
        #pragma unroll
        for (int ni = 0; ni < 4; ++ni) acc[mi][ni] = {0.f, 0.f, 0.f, 0.f};

    const int KT = K >> 5;

    auto stage = [&](int buf, int kt) {
        const char* ab = Abase + (size_t)kt * 64;
        char* la = smem + buf * 12288;
        #pragma unroll
        for (int c = 0; c < 4; ++c) {
            int p = wv * 4096 + c * 1024 + ln * 16;
            int r = p >> 6;
            int cc = (p & 63) ^ (((p >> 7) & 3) << 4);
            gld16(ab + (size_t)r * sA + cc, la + wv * 4096 + c * 1024);
        }
        const char* bb = Bbase + (size_t)kt * 64;
        char* lb = smem + buf * 12288 + 8192;
        #pragma unroll
        for (int c = 0; c < 2; ++c) {
            int p = wv * 2048 + c * 1024 + ln * 16;
            int r = p >> 6;
            int cc = (p & 63) ^ (((p >> 7) & 3) << 4);
            gld16(bb + (size_t)r * sB + cc, lb + wv * 2048 + c * 1024);
        }
    };

    stage(0, 0);
    for (int kt = 0; kt < KT; ++kt) {
        __syncthreads();                   // drains vmcnt -> buf[kt&1] ready
        if (kt + 1 < KT) stage((kt + 1) & 1, kt + 1);
        const char* la = smem + (kt & 1) * 12288;
        const char* lb = la + 8192;
        short8 af[4], bfv[4];
        #pragma unroll
        for (int mi = 0; mi < 4; ++mi) {
            int r = wv * 64 + mi * 16 + lr;
            af[mi] = *(const short8*)(la + r * 64 + ((lq * 16) ^ (((r >> 1) & 3) << 4)));
        }
        #pragma unroll
        for (int ni = 0; ni < 4; ++ni) {
            int n = ni * 16 + lr;
            bfv[ni] = *(const short8*)(lb + n * 64 + ((lq * 16) ^ (((n >> 1) & 3) << 4)));
        }
        #pragma unroll
        for (int mi = 0; mi < 4; ++mi)
            #pragma unroll
            for (int ni = 0; ni < 4; ++ni)
                acc[mi][ni] = __builtin_amdgcn_mfma_f32_16x16x32_bf16(
                    af[mi], bfv[ni], acc[mi][ni], 0, 0, 0);
    }

    // Epilogue. D mapping: row = lq*4+i, col = lr (within 16x16 fragment).
    #pragma unroll
    for (int mi = 0; mi < 4; ++mi) {
        #pragma unroll
        for (int i = 0; i < 4; ++i) {
            int gm = rm0 + wv * 64 + mi * 16 + lq * 4 + i;
            #pragma unroll
            for (int ni = 0; ni < 4; ++ni) {
                int gn = n0 + ni * 16 + lr;
                float v = acc[mi][ni][i];
                if (EPI == EPI_EMBED) {
                    if (gn < E_) v += bias[gn] + pos[(size_t)(gm & 255) * E_ + gn];
                    else v = 0.f;
                    Of[(size_t)gm * EP_ + gn] = v;
                    Ob[(size_t)gm * EP_ + gn] = f2bf(v);
                } else if (EPI == EPI_QK) {
                    if (gn < E_) {
                        int h = gn >= DH_;
                        int d = gn - h * DH_;
                        Ob[(((size_t)(gm >> 8) * NH_ + h) * 256 + (gm & 255)) * DHP_ + d] = f2bf(v);
                    } else {
                        int pi = gn - E_;            // 0..7 -> head pads d in [156,160)
                        int h = pi >> 2;
                        int d = DH_ + (pi & 3);
                        Ob[(((size_t)(gm >> 8) * NH_ + h) * 256 + (gm & 255)) * DHP_ + d] = (short)0;
                    }
                } else if (EPI == EPI_VT) {
                    if (gn < E_) {
                        int h = gn >= DH_;
                        int d = gn - h * DH_;
                        Ob[(((size_t)(gm >> 8) * NH_ + h) * 192 + d) * 256 + (gm & 255)] = f2bf(v);
                    }
                } else if (EPI == EPI_AV) {
                    if (gn < DH_) {
                        int b = z >> 1, h = z & 1;
                        Of[((size_t)b * 256 + gm) * EP_ + h * DH_ + gn] = v;
                    }
                } else if (EPI == EPI_GELU_BF) {
                    float bi = (gn < E_) ? bias[gn] : 0.f;
                    v += bi;
                    v = 0.5f * v * (1.f + erff(v * 0.70710678118654752f));
                    if (gn >= E_) v = 0.f;
                    Ob[(size_t)gm * EP_ + gn] = f2bf(v);
                } else if (EPI == EPI_GELU_F32) {
                    float bi = (gn < E_) ? bias[gn] : 0.f;
                    v += bi;
                    v = 0.5f * v * (1.f + erff(v * 0.70710678118654752f));
                    if (gn >= E_) v = 0.f;
                    Of[(size_t)gm * EP_ + gn] = v;
                } else if (EPI == EPI_OUT) {
                    v += bias[gn];
                    Of[(size_t)gm * 256 + gn] = v;
                }
            }
        }
    }
}

// ---------------------------------------------------------------------------
// Fused score + softmax: per block (q-group of 64 rows, bh), compute
// 64x256 scores via MFMA (K=DHP), row-softmax across 4 waves, write bf16 P.
// ---------------------------------------------------------------------------
__global__ __launch_bounds__(256)
void score_softmax_kernel(const short* __restrict__ Qh, const short* __restrict__ Kh,
                          short* __restrict__ P) {
    __shared__ __align__(16) char smem[40960];  // 2 bufs x (4KB Q + 16KB K)
    __shared__ float redm[4][64];
    __shared__ float reds[4][64];
    const int tid = threadIdx.x;
    const int wv = tid >> 6, ln = tid & 63;
    const int lr = ln & 15, lq = ln >> 4;
    const int z = blockIdx.y;
    const int q0 = blockIdx.x * 64;

    const size_t sA = DHP_ * 2;  // 320 B row stride
    const char* Qbase = (const char*)(Qh + (size_t)z * 256 * DHP_) + (size_t)q0 * sA;
    const char* Kbase = (const char*)(Kh + (size_t)z * 256 * DHP_);

    f32x4 acc[4][4];
    #pragma unroll
    for (int mi = 0; mi < 4; ++mi)
        #pragma unroll
        for (int ni = 0; ni < 4; ++ni) acc[mi][ni] = {0.f, 0.f, 0.f, 0.f};

    auto stage = [&](int buf, int kt) {
        char* la = smem + buf * 20480;
        {   // Q: 64 rows x 64B = 4KB (one 16B op per thread)
            int p = tid * 16;
            int r = p >> 6;
            int cc = (p & 63) ^ (((p >> 7) & 3) << 4);
            gld16(Qbase + (size_t)kt * 64 + (size_t)r * sA + cc, la + p);
        }
        char* lb = la + 4096;
        #pragma unroll
        for (int c = 0; c < 4; ++c) {   // K: 256 rows x 64B = 16KB
            int p = c * 4096 + tid * 16;
            int r = p >> 6;
            int cc = (p & 63) ^ (((p >> 7) & 3) << 4);
            gld16(Kbase + (size_t)kt * 64 + (size_t)r * sA + cc, lb + p);
        }
    };

    stage(0, 0);
    for (int kt = 0; kt < 5; ++kt) {     // K = 160 = 5 x 32
        __syncthreads();
        if (kt + 1 < 5) stage((kt + 1) & 1, kt + 1);
        const char* la = smem + (kt & 1) * 20480;
        const char* lb = la + 4096;
        short8 af[4], bfv[4];
        #pragma unroll
        for (int mi = 0; mi < 4; ++mi) {
            int r = mi * 16 + lr;
            af[mi] = *(const short8*)(la + r * 64 + ((lq * 16) ^ (((r >> 1) & 3) << 4)));
        }
        #pragma unroll
        for (int ni = 0; ni < 4; ++ni) {
            int n = wv * 64 + ni * 16 + lr;
            bfv[ni] = *(const short8*)(lb + n * 64 + ((lq * 16) ^ (((n >> 1) & 3) << 4)));
        }
        #pragma unroll
        for (int mi = 0; mi < 4; ++mi)
            #pragma unroll
            for (int ni = 0; ni < 4; ++ni)
                acc[mi][ni] = __builtin_amdgcn_mfma_f32_16x16x32_bf16(
                    af[mi], bfv[ni], acc[mi][ni], 0, 0, 0);
    }

    // scale
    const float scale = 0.08006407690254357f;   // 156^-0.5
    #pragma unroll
    for (int mi = 0; mi < 4; ++mi)
        #pragma unroll
        for (int ni = 0; ni < 4; ++ni)
            #pragma unroll
            for (int i = 0; i < 4; ++i) acc[mi][ni][i] *= scale;

    // row max: in-reg over ni, shfl over the 16-lane lr group, LDS over waves
    #pragma unroll
    for (int mi = 0; mi < 4; ++mi) {
        #pragma unroll
        for (int i = 0; i < 4; ++i) {
            float m = fmaxf(fmaxf(acc[mi][0][i], acc[mi][1][i]),
                            fmaxf(acc[mi][2][i], acc[mi][3][i]));
            #pragma unroll
            for (int off = 1; off < 16; off <<= 1) m = fmaxf(m, __shfl_xor(m, off));
            if (lr == 0) redm[wv][mi * 16 + lq * 4 + i] = m;
        }
    }
    __syncthreads();
    #pragma unroll
    for (int mi = 0; mi < 4; ++mi) {
        #pragma unroll
        for (int i = 0; i < 4; ++i) {
            int rl = mi * 16 + lq * 4 + i;
            float m = fmaxf(fmaxf(redm[0][rl], redm[1][rl]),
                            fmaxf(redm[2][rl], redm[3][rl]));
            float s = 0.f;
            #pragma unroll
            for (int ni = 0; ni < 4; ++ni) {
                float e = expf(acc[mi][ni][i] - m);
                acc[mi][ni][i] = e;
                s += e;
            }
            #pragma unroll
            for (int off = 1; off < 16; off <<= 1) s += __shfl_xor(s, off);
            if (lr == 0) reds[wv][rl] = s;
        }
    }
    __syncthreads();

    short* Pz = P + (size_t)z * 256 * 256;
    #pragma unroll
    for (int mi = 0; mi < 4; ++mi) {
        #pragma unroll
        for (int i = 0; i < 4; ++i) {
            int rl = mi * 16 + lq * 4 + i;
            float inv = 1.f / (reds[0][rl] + reds[1][rl] + reds[2][rl] + reds[3][rl]);
            int gm = q0 + rl;
            #pragma unroll
            for (int ni = 0; ni < 4; ++ni) {
                int gn = wv * 64 + ni * 16 + lr;
                Pz[(size_t)gm * 256 + gn] = f2bf(acc[mi][ni][i] * inv);
            }
        }
    }
}

// ---------------------------------------------------------------------------
// LayerNorm of (A + Bi), fp32 in (stride 320, 312 real cols),
// bf16 out (stride 320, zero pads) + optional fp32 out
// ---------------------------------------------------------------------------
template <bool DUAL>
__global__ __launch_bounds__(256)
void ln_kernel(const float* __restrict__ A, const float* __restrict__ Bi,
               const float* __restrict__ g, const float* __restrict__ beta,
               short* __restrict__ Outb, float* __restrict__ Outf) {
    int row = blockIdx.x;
    size_t base = (size_t)row * EP_;
    int tid = threadIdx.x;
    __shared__ float red[256];
    __shared__ float red2[256];

    float ya = A[base + tid] + Bi[base + tid];
    int t2 = tid + 256;
    float yb = (t2 < E_) ? A[base + t2] + Bi[base + t2] : 0.f;
    red[tid]  = ya + yb;
    red2[tid] = ya * ya + yb * yb;
    __syncthreads();
    for (int off = 128; off > 0; off >>= 1) {
        if (tid < off) { red[tid] += red[tid + off]; red2[tid] += red2[tid + off]; }
        __syncthreads();
    }
    float mean = red[0] / (float)E_;
    float var  = red2[0] / (float)E_ - mean * mean;
    float inv  = rsqrtf(var + 1e-5f);
    float oa = (ya - mean) * inv * g[tid] + beta[tid];
    Outb[base + tid] = f2bf(oa);
    if (DUAL) Outf[base + tid] = oa;
    if (t2 < E_) {
        float ob = (yb - mean) * inv * g[t2] + beta[t2];
        Outb[base + t2] = f2bf(ob);
        if (DUAL) Outf[base + t2] = ob;
    } else if (t2 < EP_) {
        Outb[base + t2] = 0;
        if (DUAL) Outf[base + t2] = 0.f;
    }
}

// ---------------------------------------------------------------------------
// Scatter + final add
// ---------------------------------------------------------------------------
__global__ __launch_bounds__(256)
void scatter_kernel(const float* __restrict__ sino, const float* __restrict__ idx,
                    const float* __restrict__ outm, float* __restrict__ dout) {
    size_t i = (size_t)blockIdx.x * 256 + threadIdx.x;
    size_t total = (size_t)B_ * T_ * V_;
    if (i >= total) return;
    int tv = (int)(i % ((size_t)T_ * V_));
    int b  = (int)(i / ((size_t)T_ * V_));
    int r  = (int)idx[(size_t)tv * 3 + 0];
    int cc = (int)idx[(size_t)tv * 3 + 1];
    float sc = idx[(size_t)tv * 3 + 2];
    size_t pos = (size_t)r * W_ + cc;
    dout[(size_t)b * H_ * W_ + pos] =
        sino[((size_t)b * C_ + (C_ - 1)) * (size_t)H_ * W_ + pos] + outm[i] * sc;
}

// ---------------------------------------------------------------------------
extern "C" void kernel_launch(void* const* d_in, const int* in_sizes, int n_in,
                              void* d_out, int out_size, void* d_ws, size_t ws_size,
                              hipStream_t stream) {
    const float* sino     = (const float*)d_in[0];
    const float* idx      = (const float*)d_in[1];
    const float* We       = (const float*)d_in[2];
    const float* be       = (const float*)d_in[3];
    const float* pos      = (const float*)d_in[4];
    const float* Wq       = (const float*)d_in[5];
    const float* Wk       = (const float*)d_in[6];
    const float* Wv       = (const float*)d_in[7];
    const float* W1       = (const float*)d_in[8];
    const float* b1       = (const float*)d_in[9];
    const float* W2       = (const float*)d_in[10];
    const float* b2       = (const float*)d_in[11];
    const float* W3       = (const float*)d_in[12];
    const float* b3       = (const float*)d_in[13];
    const float* g_att    = (const float*)d_in[14];
    const float* beta_att = (const float*)d_in[15];
    const float* g_mlp    = (const float*)d_in[16];
    const float* beta_mlp = (const float*)d_in[17];
    const float* Wu       = (const float*)d_in[18];
    const float* bu       = (const float*)d_in[19];
    float* out = (float*)d_out;
    char* w = (char*)d_ws;

    // Region layout (bytes), lifetime-based reuse
    const size_t oA = 0;                      // 62,914,560: xt_bf -> h3_f32
    const size_t oB = oA + 62914560;          // 31,457,280: Z_f32 -> h1_bf
    const size_t oC = oB + 31457280;          // 25,165,824: Z_bf -> P_bf
    const size_t oD = oC + 25165824;          // 15,728,640: Qh -> x1_bf
    const size_t oE = oD + 15728640;          // 15,728,640: Kh -> h2_bf
    const size_t oF = oE + 15728640;          // 31,457,280: Vt(18.9M) -> x1_f32
    const size_t oG = oF + 31457280;          // 31,457,280: ab_f32 -> x2_bf
    const size_t oH = oG + 31457280;          // 25,165,824: outm
    const size_t oW = oH + 25165824;          // weights

    short* xt_bf = (short*)(w + oA);
    float* h3f   = (float*)(w + oA);
    float* Zf    = (float*)(w + oB);
    short* h1b   = (short*)(w + oB);
    short* Zb    = (short*)(w + oC);
    short* Pb    = (short*)(w + oC);
    short* Qh    = (short*)(w + oD);
    short* x1b   = (short*)(w + oD);
    short* Kh    = (short*)(w + oE);
    short* h2b   = (short*)(w + oE);
    short* Vt    = (short*)(w + oF);
    float* x1f   = (float*)(w + oF);
    float* abf   = (float*)(w + oG);
    short* x2b   = (short*)(w + oG);
    float* outm  = (float*)(w + oH);
    short* We_t  = (short*)(w + oW);
    short* Wq_t  = We_t + 409600;
    short* Wk_t  = Wq_t + 102400;
    short* Wv_t  = Wk_t + 102400;
    short* W1_t  = Wv_t + 102400;
    short* W2_t  = W1_t + 102400;
    short* W3_t  = W2_t + 102400;
    short* Wu_t  = W3_t + 102400;

    // 1. gather -> bf16 xt (XCD-pinned plane-major, 16-deep ILP)
    gather_kernel<<<dim3(7680), dim3(256), 0, stream>>>(sino, idx, xt_bf);

    // 2. weight converts
    wconv_kernel<<<dim3(1600), dim3(256), 0, stream>>>(We, We_t, 1280, E_, 1280, EP_);
    wconv_kernel<<<dim3(400), dim3(256), 0, stream>>>(Wq, Wq_t, E_, E_, EP_, EP_);
    wconv_kernel<<<dim3(400), dim3(256), 0, stream>>>(Wk, Wk_t, E_, E_, EP_, EP_);
    wconv_kernel<<<dim3(400), dim3(256), 0, stream>>>(Wv, Wv_t, E_, E_, EP_, EP_);
    wconv_kernel<<<dim3(400), dim3(256), 0, stream>>>(W1, W1_t, E_, E_, EP_, EP_);
    wconv_kernel<<<dim3(400), dim3(256), 0, stream>>>(W2, W2_t, E_, E_, EP_, EP_);
    wconv_kernel<<<dim3(400), dim3(256), 0, stream>>>(W3, W3_t, E_, E_, EP_, EP_);
    wconv_kernel<<<dim3(320), dim3(256), 0, stream>>>(Wu, Wu_t, E_, 256, EP_, 256);

    // 3. Z = xt @ We + be + pos  (fp32 + bf16)
    mgemm<EPI_EMBED><<<dim3(EP_ / 64, M_ / 128), dim3(128), 0, stream>>>(
        xt_bf, We_t, be, pos, Zf, Zb, CV_, CV_, CV_);

    // 4. Q, K (head layout, pads zeroed in epilogue), V (transposed head layout)
    mgemm<EPI_QK><<<dim3(EP_ / 64, M_ / 128), dim3(128), 0, stream>>>(
        Zb, Wq_t, nullptr, nullptr, nullptr, Qh, EP_, EP_, EP_);
    mgemm<EPI_QK><<<dim3(EP_ / 64, M_ / 128), dim3(128), 0, stream>>>(
        Zb, Wk_t, nullptr, nullptr, nullptr, Kh, EP_, EP_, EP_);
    mgemm<EPI_VT><<<dim3(EP_ / 64, M_ / 128), dim3(128), 0, stream>>>(
        Zb, Wv_t, nullptr, nullptr, nullptr, Vt, EP_, EP_, EP_);

    // 5. attention: fused score+softmax -> P ; then A = P @ V
    score_softmax_kernel<<<dim3(4, 192), dim3(256), 0, stream>>>(Qh, Kh, Pb);
    mgemm<EPI_AV><<<dim3(3, 2, B_ * NH_), dim3(128), 0, stream>>>(
        Pb, Vt, nullptr, nullptr, abf, nullptr, 256, 256, 256);

    // 6. x1 = LN(Z + a)  (fp32 + bf16)
    ln_kernel<true><<<dim3(M_), dim3(256), 0, stream>>>(Zf, abf, g_att, beta_att, x1b, x1f);

    // 7. MLP
    mgemm<EPI_GELU_BF><<<dim3(EP_ / 64, M_ / 128), dim3(128), 0, stream>>>(
        x1b, W1_t, b1, nullptr, nullptr, h1b, EP_, EP_, EP_);
    mgemm<EPI_GELU_BF><<<dim3(EP_ / 64, M_ / 128), dim3(128), 0, stream>>>(
        h1b, W2_t, b2, nullptr, nullptr, h2b, EP_, EP_, EP_);
    mgemm<EPI_GELU_F32><<<dim3(EP_ / 64, M_ / 128), dim3(128), 0, stream>>>(
        h2b, W3_t, b3, nullptr, h3f, nullptr, EP_, EP_, EP_);

    // 8. x2 = LN(x1 + h)  (bf16 only)
    ln_kernel<false><<<dim3(M_), dim3(256), 0, stream>>>(x1f, h3f, g_mlp, beta_mlp, x2b, nullptr);

    // 9. out = x2 @ Wu + bu (fp32)
    mgemm<EPI_OUT><<<dim3(256 / 64, M_ / 128), dim3(128), 0, stream>>>(
        x2b, Wu_t, bu, nullptr, outm, nullptr, EP_, EP_, EP_);

    // 10. scatter
    scatter_kernel<<<dim3((B_ * T_ * V_) / 256), dim3(256), 0, stream>>>(sino, idx, outm, out);
}

// Round 8
// 791.072 us; speedup vs baseline: 6.0357x; 1.0074x over previous
//
#include <hip/hip_runtime.h>
#include <math.h>

// Problem constants
constexpr int B_  = 96;
constexpr int T_  = 256;
constexpr int V_  = 256;
constexpr int C_  = 5;
constexpr int H_  = 256;
constexpr int W_  = 256;
constexpr int NH_ = 2;
constexpr int DH_ = 156;
constexpr int E_  = 312;
constexpr int EP_ = 320;   // padded E
constexpr int DHP_ = 160;  // padded DH
constexpr int CV_ = 1280;
constexpr int M_  = B_ * T_;  // 24576

typedef short short8 __attribute__((ext_vector_type(8)));
typedef float f32x4 __attribute__((ext_vector_type(4)));

__device__ inline short f2bf(float f) {
    unsigned u = __builtin_bit_cast(unsigned, f);
    u = (u + 0x7fff + ((u >> 16) & 1)) >> 16;
    return (short)u;
}

__device__ inline void gld16(const void* g, void* l) {
    __builtin_amdgcn_global_load_lds(
        (const __attribute__((address_space(1))) unsigned*)g,
        (__attribute__((address_space(3))) unsigned*)l, 16, 0, 0);
}

// ---------------------------------------------------------------------------
// Gather -> bf16 xt [M][1280], XCD-pinned plane-major, 16-deep load ILP.
// sched_barrier(0) fences force ALL 16 divergent loads in flight before the
// first dependent store (round-7 showed the compiler otherwise re-fuses the
// phases down to VGPR=20 / ~2 loads in flight).
// ---------------------------------------------------------------------------
__global__ __launch_bounds__(256)
void gather_kernel(const float* __restrict__ sino, const float* __restrict__ idx,
                   short* __restrict__ xt) {
    int bid = blockIdx.x;
    int xcd = bid & 7, slot = bid >> 3;
    int sub = slot & 15, pidx = slot >> 4;
    int plane = pidx * 8 + xcd;          // [0, 480)
    int b = plane / C_, ch = plane - b * C_;
    const float* sp = sino + ((size_t)b * C_ + ch) * (H_ * W_);
    int tid = threadIdx.x;

    int addr[16];
    #pragma unroll
    for (int tt = 0; tt < 16; ++tt) {
        int tv = (sub * 16 + tt) * 256 + tid;
        int r  = (int)idx[(size_t)tv * 3 + 0];
        int cc = (int)idx[(size_t)tv * 3 + 1];
        addr[tt] = r * W_ + cc;
    }
    __builtin_amdgcn_sched_barrier(0);
    float pix[16];
    #pragma unroll
    for (int tt = 0; tt < 16; ++tt) pix[tt] = sp[addr[tt]];
    __builtin_amdgcn_sched_barrier(0);
    size_t dbase = (((size_t)b * T_ + sub * 16) * C_ + ch) * V_ + tid;
    #pragma unroll
    for (int tt = 0; tt < 16; ++tt)
        xt[dbase + (size_t)tt * (C_ * V_)] = f2bf(pix[tt]);
}

// ---------------------------------------------------------------------------
// Weight convert+transpose: Wt[n][k] (bf16, [NP][KP], zero-padded)
// ---------------------------------------------------------------------------
__global__ __launch_bounds__(256)
void wconv_kernel(const float* __restrict__ Wsrc, short* __restrict__ Wt,
                  int Ks, int Ns, int KP, int NP) {
    int idx = blockIdx.x * 256 + threadIdx.x;
    if (idx >= NP * KP) return;
    int n = idx / KP, k = idx - n * KP;
    Wt[idx] = (n < Ns && k < Ks) ? f2bf(Wsrc[(size_t)k * Ns + n]) : (short)0;
}

// ---------------------------------------------------------------------------
// MFMA GEMM: C = A[M,K](bf16) @ Bt[N,K]^T(bf16), per-EPI epilogue.
// Block: 256 threads = 4 waves. Tile BM=256 (wave: 64 rows), BN=64. BK=32.
// LDS/step: A 16KB + B 4KB; double-buffered = 40KB.
// ---------------------------------------------------------------------------
#define EPI_EMBED    0
#define EPI_QK       1
#define EPI_VT       2
#define EPI_AV       4
#define EPI_GELU_BF  5
#define EPI_GELU_F32 6
#define EPI_OUT      7

template <int EPI>
__global__ __launch_bounds__(256)
void mgemm(const short* __restrict__ Aall, const short* __restrict__ Ball,
           const float* __restrict__ bias, const float* __restrict__ pos,
           float* __restrict__ Of, short* __restrict__ Ob,
           int K, int strideA, int strideB) {
    __shared__ __align__(16) char smem[40960];   // 2 bufs x (16KB A + 4KB B)
    const int tid = threadIdx.x;
    const int wv = tid >> 6, ln = tid & 63;
    const int lr = ln & 15, lq = ln >> 4;
    const int z = blockIdx.z;

    const short* A;
    const short* Bt;
    if (EPI == EPI_AV) { A = Aall + (size_t)z * 256 * 256;  Bt = Ball + (size_t)z * 192 * 256; }
    else               { A = Aall; Bt = Ball; }

    const int rm0 = blockIdx.y * 256;
    const int n0  = blockIdx.x * 64;
    const char* Abase = (const char*)(A + (size_t)rm0 * strideA);
    const char* Bbase = (const char*)(Bt + (size_t)n0 * strideB);
    const size_t sA = (size_t)strideA * 2, sB = (size_t)strideB * 2;

    f32x4 acc[4][4];
    #pragma unroll
    for (int mi = 0; mi < 4; ++mi)
        #pragma unroll
        for (int ni = 0; ni < 4; ++ni) acc[mi][ni] = {0.f, 0.f, 0.f, 0.f};

    const int KT = K >> 5;

    auto stage = [&](int buf, int kt) {
        const char* ab = Abase + (size_t)kt * 64;
        char* la = smem + buf * 20480;
        #pragma unroll
        for (int c = 0; c < 4; ++c) {          // A: 256 rows x 64B = 16KB
            int p = c * 4096 + tid * 16;
            int r = p >> 6;
            int cc = (p & 63) ^ (((p >> 7) & 3) << 4);
            gld16(ab + (size_t)r * sA + cc, la + c * 4096 + wv * 1024);
        }
        {                                       // B: 64 rows x 64B = 4KB
            int p = tid * 16;
            int r = p >> 6;
            int cc = (p & 63) ^ (((p >> 7) & 3) << 4);
            gld16(Bbase + (size_t)kt * 64 + (size_t)r * sB + cc,
                  la + 16384 + wv * 1024);
        }
    };

    stage(0, 0);
    for (int kt = 0; kt < KT; ++kt) {
        __syncthreads();                   // drains vmcnt -> buf[kt&1] ready
        if (kt + 1 < KT) stage((kt + 1) & 1, kt + 1);
        const char* la = smem + (kt & 1) * 20480;
        const char* lb = la + 16384;
        short8 af[4], bfv[4];
        #pragma unroll
        for (int mi = 0; mi < 4; ++mi) {
            int r = wv * 64 + mi * 16 + lr;
            af[mi] = *(const short8*)(la + r * 64 + ((lq * 16) ^ (((r >> 1) & 3) << 4)));
        }
        #pragma unroll
        for (int ni = 0; ni < 4; ++ni) {
            int n = ni * 16 + lr;
            bfv[ni] = *(const short8*)(lb + n * 64 + ((lq * 16) ^ (((n >> 1) & 3) << 4)));
        }
        #pragma unroll
        for (int mi = 0; mi < 4; ++mi)
            #pragma unroll
            for (int ni = 0; ni < 4; ++ni)
                acc[mi][ni] = __builtin_amdgcn_mfma_f32_16x16x32_bf16(
                    af[mi], bfv[ni], acc[mi][ni], 0, 0, 0);
    }

    // Epilogue. D mapping: row = lq*4+i, col = lr (within 16x16 fragment).
    #pragma unroll
    for (int mi = 0; mi < 4; ++mi) {
        #pragma unroll
        for (int i = 0; i < 4; ++i) {
            int gm = rm0 + wv * 64 + mi * 16 + lq * 4 + i;
            #pragma unroll
            for (int ni = 0; ni < 4; ++ni) {
                int gn = n0 + ni * 16 + lr;
                float v = acc[mi][ni][i];
                if (EPI == EPI_EMBED) {
                    if (gn < E_) v += bias[gn] + pos[(size_t)(gm & 255) * E_ + gn];
                    else v = 0.f;
                    Of[(size_t)gm * EP_ + gn] = v;
                    Ob[(size_t)gm * EP_ + gn] = f2bf(v);
                } else if (EPI == EPI_QK) {
                    if (gn < E_) {
                        int h = gn >= DH_;
                        int d = gn - h * DH_;
                        Ob[(((size_t)(gm >> 8) * NH_ + h) * 256 + (gm & 255)) * DHP_ + d] = f2bf(v);
                    } else {
                        int pi = gn - E_;            // 0..7 -> head pads d in [156,160)
                        int h = pi >> 2;
                        int d = DH_ + (pi & 3);
                        Ob[(((size_t)(gm >> 8) * NH_ + h) * 256 + (gm & 255)) * DHP_ + d] = (short)0;
                    }
                } else if (EPI == EPI_VT) {
                    if (gn < E_) {
                        int h = gn >= DH_;
                        int d = gn - h * DH_;
                        Ob[(((size_t)(gm >> 8) * NH_ + h) * 192 + d) * 256 + (gm & 255)] = f2bf(v);
                    }
                } else if (EPI == EPI_AV) {
                    if (gn < DH_) {
                        int b = z >> 1, h = z & 1;
                        Of[((size_t)b * 256 + gm) * EP_ + h * DH_ + gn] = v;
                    }
                } else if (EPI == EPI_GELU_BF) {
                    float bi = (gn < E_) ? bias[gn] : 0.f;
                    v += bi;
                    v = 0.5f * v * (1.f + erff(v * 0.70710678118654752f));
                    if (gn >= E_) v = 0.f;
                    Ob[(size_t)gm * EP_ + gn] = f2bf(v);
                } else if (EPI == EPI_GELU_F32) {
                    float bi = (gn < E_) ? bias[gn] : 0.f;
                    v += bi;
                    v = 0.5f * v * (1.f + erff(v * 0.70710678118654752f));
                    if (gn >= E_) v = 0.f;
                    Of[(size_t)gm * EP_ + gn] = v;
                } else if (EPI == EPI_OUT) {
                    v += bias[gn];
                    Of[(size_t)gm * 256 + gn] = v;
                }
            }
        }
    }
}

// ---------------------------------------------------------------------------
// Fused score + softmax: per block (q-group of 64 rows, bh), compute
// 64x256 scores via MFMA (K=DHP), row-softmax across 4 waves, write bf16 P.
// ---------------------------------------------------------------------------
__global__ __launch_bounds__(256)
void score_softmax_kernel(const short* __restrict__ Qh, const short* __restrict__ Kh,
                          short* __restrict__ P) {
    __shared__ __align__(16) char smem[40960];  // 2 bufs x (4KB Q + 16KB K)
    __shared__ float redm[4][64];
    __shared__ float reds[4][64];
    const int tid = threadIdx.x;
    const int wv = tid >> 6, ln = tid & 63;
    const int lr = ln & 15, lq = ln >> 4;
    const int z = blockIdx.y;
    const int q0 = blockIdx.x * 64;

    const size_t sA = DHP_ * 2;  // 320 B row stride
    const char* Qbase = (const char*)(Qh + (size_t)z * 256 * DHP_) + (size_t)q0 * sA;
    const char* Kbase = (const char*)(Kh + (size_t)z * 256 * DHP_);

    f32x4 acc[4][4];
    #pragma unroll
    for (int mi = 0; mi < 4; ++mi)
        #pragma unroll
        for (int ni = 0; ni < 4; ++ni) acc[mi][ni] = {0.f, 0.f, 0.f, 0.f};

    auto stage = [&](int buf, int kt) {
        char* la = smem + buf * 20480;
        {   // Q: 64 rows x 64B = 4KB (one 16B op per thread)
            int p = tid * 16;
            int r = p >> 6;
            int cc = (p & 63) ^ (((p >> 7) & 3) << 4);
            gld16(Qbase + (size_t)kt * 64 + (size_t)r * sA + cc, la + wv * 1024);
        }
        char* lb = la + 4096;
        #pragma unroll
        for (int c = 0; c < 4; ++c) {   // K: 256 rows x 64B = 16KB
            int p = c * 4096 + tid * 16;
            int r = p >> 6;
            int cc = (p & 63) ^ (((p >> 7) & 3) << 4);
            gld16(Kbase + (size_t)kt * 64 + (size_t)r * sA + cc, lb + c * 4096 + wv * 1024);
        }
    };

    stage(0, 0);
    for (int kt = 0; kt < 5; ++kt) {     // K = 160 = 5 x 32
        __syncthreads();
        if (kt + 1 < 5) stage((kt + 1) & 1, kt + 1);
        const char* la = smem + (kt & 1) * 20480;
        const char* lb = la + 4096;
        short8 af[4], bfv[4];
        #pragma unroll
        for (int mi = 0; mi < 4; ++mi) {
            int r = mi * 16 + lr;
            af[mi] = *(const short8*)(la + r * 64 + ((lq * 16) ^ (((r >> 1) & 3) << 4)));
        }
        #pragma unroll
        for (int ni = 0; ni < 4; ++ni) {
            int n = wv * 64 + ni * 16 + lr;
            bfv[ni] = *(const short8*)(lb + n * 64 + ((lq * 16) ^ (((n >> 1) & 3) << 4)));
        }
        #pragma unroll
        for (int mi = 0; mi < 4; ++mi)
            #pragma unroll
            for (int ni = 0; ni < 4; ++ni)
                acc[mi][ni] = __builtin_amdgcn_mfma_f32_16x16x32_bf16(
                    af[mi], bfv[ni], acc[mi][ni], 0, 0, 0);
    }

    // scale
    const float scale = 0.08006407690254357f;   // 156^-0.5
    #pragma unroll
    for (int mi = 0; mi < 4; ++mi)
        #pragma unroll
        for (int ni = 0; ni < 4; ++ni)
            #pragma unroll
            for (int i = 0; i < 4; ++i) acc[mi][ni][i] *= scale;

    // row max: in-reg over ni, shfl over the 16-lane lr group, LDS over waves
    #pragma unroll
    for (int mi = 0; mi < 4; ++mi) {
        #pragma unroll
        for (int i = 0; i < 4; ++i) {
            float m = fmaxf(fmaxf(acc[mi][0][i], acc[mi][1][i]),
                            fmaxf(acc[mi][2][i], acc[mi][3][i]));
            #pragma unroll
            for (int off = 1; off < 16; off <<= 1) m = fmaxf(m, __shfl_xor(m, off));
            if (lr == 0) redm[wv][mi * 16 + lq * 4 + i] = m;
        }
    }
    __syncthreads();
    #pragma unroll
    for (int mi = 0; mi < 4; ++mi) {
        #pragma unroll
        for (int i = 0; i < 4; ++i) {
            int rl = mi * 16 + lq * 4 + i;
            float m = fmaxf(fmaxf(redm[0][rl], redm[1][rl]),
                            fmaxf(redm[2][rl], redm[3][rl]));
            float s = 0.f;
            #pragma unroll
            for (int ni = 0; ni < 4; ++ni) {
                float e = expf(acc[mi][ni][i] - m);
                acc[mi][ni][i] = e;
                s += e;
            }
            #pragma unroll
            for (int off = 1; off < 16; off <<= 1) s += __shfl_xor(s, off);
            if (lr == 0) reds[wv][rl] = s;
        }
    }
    __syncthreads();

    short* Pz = P + (size_t)z * 256 * 256;
    #pragma unroll
    for (int mi = 0; mi < 4; ++mi) {
        #pragma unroll
        for (int i = 0; i < 4; ++i) {
            int rl = mi * 16 + lq * 4 + i;
            float inv = 1.f / (reds[0][rl] + reds[1][rl] + reds[2][rl] + reds[3][rl]);
            int gm = q0 + rl;
            #pragma unroll
            for (int ni = 0; ni < 4; ++ni) {
                int gn = wv * 64 + ni * 16 + lr;
                Pz[(size_t)gm * 256 + gn] = f2bf(acc[mi][ni][i] * inv);
            }
        }
    }
}

// ---------------------------------------------------------------------------
// LayerNorm of (A + Bi), fp32 in (stride 320, 312 real cols),
// bf16 out (stride 320, zero pads) + optional fp32 out
// ---------------------------------------------------------------------------
template <bool DUAL>
__global__ __launch_bounds__(256)
void ln_kernel(const float* __restrict__ A, const float* __restrict__ Bi,
               const float* __restrict__ g, const float* __restrict__ beta,
               short* __restrict__ Outb, float* __restrict__ Outf) {
    int row = blockIdx.x;
    size_t base = (size_t)row * EP_;
    int tid = threadIdx.x;
    __shared__ float red[256];
    __shared__ float red2[256];

    float ya = A[base + tid] + Bi[base + tid];
    int t2 = tid + 256;
    float yb = (t2 < E_) ? A[base + t2] + Bi[base + t2] : 0.f;
    red[tid]  = ya + yb;
    red2[tid] = ya * ya + yb * yb;
    __syncthreads();
    for (int off = 128; off > 0; off >>= 1) {
        if (tid < off) { red[tid] += red[tid + off]; red2[tid] += red2[tid + off]; }
        __syncthreads();
    }
    float mean = red[0] / (float)E_;
    float var  = red2[0] / (float)E_ - mean * mean;
    float inv  = rsqrtf(var + 1e-5f);
    float oa = (ya - mean) * inv * g[tid] + beta[tid];
    Outb[base + tid] = f2bf(oa);
    if (DUAL) Outf[base + tid] = oa;
    if (t2 < E_) {
        float ob = (yb - mean) * inv * g[t2] + beta[t2];
        Outb[base + t2] = f2bf(ob);
        if (DUAL) Outf[base + t2] = ob;
    } else if (t2 < EP_) {
        Outb[base + t2] = 0;
        if (DUAL) Outf[base + t2] = 0.f;
    }
}

// ---------------------------------------------------------------------------
// Scatter + final add
// ---------------------------------------------------------------------------
__global__ __launch_bounds__(256)
void scatter_kernel(const float* __restrict__ sino, const float* __restrict__ idx,
                    const float* __restrict__ outm, float* __restrict__ dout) {
    size_t i = (size_t)blockIdx.x * 256 + threadIdx.x;
    size_t total = (size_t)B_ * T_ * V_;
    if (i >= total) return;
    int tv = (int)(i % ((size_t)T_ * V_));
    int b  = (int)(i / ((size_t)T_ * V_));
    int r  = (int)idx[(size_t)tv * 3 + 0];
    int cc = (int)idx[(size_t)tv * 3 + 1];
    float sc = idx[(size_t)tv * 3 + 2];
    size_t pos = (size_t)r * W_ + cc;
    dout[(size_t)b * H_ * W_ + pos] =
        sino[((size_t)b * C_ + (C_ - 1)) * (size_t)H_ * W_ + pos] + outm[i] * sc;
}

// ---------------------------------------------------------------------------
extern "C" void kernel_launch(void* const* d_in, const int* in_sizes, int n_in,
                              void* d_out, int out_size, void* d_ws, size_t ws_size,
                              hipStream_t stream) {
    const float* sino     = (const float*)d_in[0];
    const float* idx      = (const float*)d_in[1];
    const float* We       = (const float*)d_in[2];
    const float* be       = (const float*)d_in[3];
    const float* pos      = (const float*)d_in[4];
    const float* Wq       = (const float*)d_in[5];
    const float* Wk       = (const float*)d_in[6];
    const float* Wv       = (const float*)d_in[7];
    const float* W1       = (const float*)d_in[8];
    const float* b1       = (const float*)d_in[9];
    const float* W2       = (const float*)d_in[10];
    const float* b2       = (const float*)d_in[11];
    const float* W3       = (const float*)d_in[12];
    const float* b3       = (const float*)d_in[13];
    const float* g_att    = (const float*)d_in[14];
    const float* beta_att = (const float*)d_in[15];
    const float* g_mlp    = (const float*)d_in[16];
    const float* beta_mlp = (const float*)d_in[17];
    const float* Wu       = (const float*)d_in[18];
    const float* bu       = (const float*)d_in[19];
    float* out = (float*)d_out;
    char* w = (char*)d_ws;

    // Region layout (bytes), lifetime-based reuse
    const size_t oA = 0;                      // 62,914,560: xt_bf -> h3_f32
    const size_t oB = oA + 62914560;          // 31,457,280: Z_f32 -> h1_bf
    const size_t oC = oB + 31457280;          // 25,165,824: Z_bf -> P_bf
    const size_t oD = oC + 25165824;          // 15,728,640: Qh -> x1_bf
    const size_t oE = oD + 15728640;          // 15,728,640: Kh -> h2_bf
    const size_t oF = oE + 15728640;          // 31,457,280: Vt(18.9M) -> x1_f32
    const size_t oG = oF + 31457280;          // 31,457,280: ab_f32 -> x2_bf
    const size_t oH = oG + 31457280;          // 25,165,824: outm
    const size_t oW = oH + 25165824;          // weights

    short* xt_bf = (short*)(w + oA);
    float* h3f   = (float*)(w + oA);
    float* Zf    = (float*)(w + oB);
    short* h1b   = (short*)(w + oB);
    short* Zb    = (short*)(w + oC);
    short* Pb    = (short*)(w + oC);
    short* Qh    = (short*)(w + oD);
    short* x1b   = (short*)(w + oD);
    short* Kh    = (short*)(w + oE);
    short* h2b   = (short*)(w + oE);
    short* Vt    = (short*)(w + oF);
    float* x1f   = (float*)(w + oF);
    float* abf   = (float*)(w + oG);
    short* x2b   = (short*)(w + oG);
    float* outm  = (float*)(w + oH);
    short* We_t  = (short*)(w + oW);
    short* Wq_t  = We_t + 409600;
    short* Wk_t  = Wq_t + 102400;
    short* Wv_t  = Wk_t + 102400;
    short* W1_t  = Wv_t + 102400;
    short* W2_t  = W1_t + 102400;
    short* W3_t  = W2_t + 102400;
    short* Wu_t  = W3_t + 102400;

    // 1. gather -> bf16 xt (XCD-pinned plane-major, fenced 16-deep ILP)
    gather_kernel<<<dim3(7680), dim3(256), 0, stream>>>(sino, idx, xt_bf);

    // 2. weight converts
    wconv_kernel<<<dim3(1600), dim3(256), 0, stream>>>(We, We_t, 1280, E_, 1280, EP_);
    wconv_kernel<<<dim3(400), dim3(256), 0, stream>>>(Wq, Wq_t, E_, E_, EP_, EP_);
    wconv_kernel<<<dim3(400), dim3(256), 0, stream>>>(Wk, Wk_t, E_, E_, EP_, EP_);
    wconv_kernel<<<dim3(400), dim3(256), 0, stream>>>(Wv, Wv_t, E_, E_, EP_, EP_);
    wconv_kernel<<<dim3(400), dim3(256), 0, stream>>>(W1, W1_t, E_, E_, EP_, EP_);
    wconv_kernel<<<dim3(400), dim3(256), 0, stream>>>(W2, W2_t, E_, E_, EP_, EP_);
    wconv_kernel<<<dim3(400), dim3(256), 0, stream>>>(W3, W3_t, E_, E_, EP_, EP_);
    wconv_kernel<<<dim3(320), dim3(256), 0, stream>>>(Wu, Wu_t, E_, 256, EP_, 256);

    // 3. Z = xt @ We + be + pos  (fp32 + bf16)
    mgemm<EPI_EMBED><<<dim3(EP_ / 64, M_ / 256), dim3(256), 0, stream>>>(
        xt_bf, We_t, be, pos, Zf, Zb, CV_, CV_, CV_);

    // 4. Q, K (head layout, pads zeroed in epilogue), V (transposed head layout)
    mgemm<EPI_QK><<<dim3(EP_ / 64, M_ / 256), dim3(256), 0, stream>>>(
        Zb, Wq_t, nullptr, nullptr, nullptr, Qh, EP_, EP_, EP_);
    mgemm<EPI_QK><<<dim3(EP_ / 64, M_ / 256), dim3(256), 0, stream>>>(
        Zb, Wk_t, nullptr, nullptr, nullptr, Kh, EP_, EP_, EP_);
    mgemm<EPI_VT><<<dim3(EP_ / 64, M_ / 256), dim3(256), 0, stream>>>(
        Zb, Wv_t, nullptr, nullptr, nullptr, Vt, EP_, EP_, EP_);

    // 5. attention: fused score+softmax -> P ; then A = P @ V
    score_softmax_kernel<<<dim3(4, 192), dim3(256), 0, stream>>>(Qh, Kh, Pb);
    mgemm<EPI_AV><<<dim3(3, 1, B_ * NH_), dim3(256), 0, stream>>>(
        Pb, Vt, nullptr, nullptr, abf, nullptr, 256, 256, 256);

    // 6. x1 = LN(Z + a)  (fp32 + bf16)
    ln_kernel<true><<<dim3(M_), dim3(256), 0, stream>>>(Zf, abf, g_att, beta_att, x1b, x1f);

    // 7. MLP
    mgemm<EPI_GELU_BF><<<dim3(EP_ / 64, M_ / 256), dim3(256), 0, stream>>>(
        x1b, W1_t, b1, nullptr, nullptr, h1b, EP_, EP_, EP_);
    mgemm<EPI_GELU_BF><<<dim3(EP_ / 64, M_ / 256), dim3(256), 0, stream>>>(
        h1b, W2_t, b2, nullptr, nullptr, h2b, EP_, EP_, EP_);
    mgemm<EPI_GELU_F32><<<dim3(EP_ / 64, M_ / 256), dim3(256), 0, stream>>>(
        h2b, W3_t, b3, nullptr, h3f, nullptr, EP_, EP_, EP_);

    // 8. x2 = LN(x1 + h)  (bf16 only)
    ln_kernel<false><<<dim3(M_), dim3(256), 0, stream>>>(x1f, h3f, g_mlp, beta_mlp, x2b, nullptr);

    // 9. out = x2 @ Wu + bu (fp32)
    mgemm<EPI_OUT><<<dim3(256 / 64, M_ / 256), dim3(256), 0, stream>>>(
        x2b, Wu_t, bu, nullptr, outm, nullptr, EP_, EP_, EP_);

    // 10. scatter
    scatter_kernel<<<dim3((B_ * T_ * V_) / 256), dim3(256), 0, stream>>>(sino, idx, outm, out);
}